// Round 4
// baseline (1145.867 us; speedup 1.0000x reference)
//
#include <hip/hip_runtime.h>

#define NN 20000
#define EE 320000
#define KK 2000
#define SCALE 0.08838834764831845f
#define PSPLIT 16

typedef const float* cfp;
typedef __attribute__((ext_vector_type(8))) short sh8;
typedef __attribute__((ext_vector_type(4))) float f32x4;

static __device__ __forceinline__ float4 ld4(const float* p){ return *reinterpret_cast<const float4*>(p); }
static __device__ __forceinline__ float2 ld2(const float* p){ return *reinterpret_cast<const float2*>(p); }
static __device__ __forceinline__ void st4(float* p, float4 v){ *reinterpret_cast<float4*>(p) = v; }

static __device__ __forceinline__ unsigned short f2bf(float f){
    unsigned int u = __float_as_uint(f);
    u = (u + 0x7FFFu + ((u >> 16) & 1u)) >> 16;
    return (unsigned short)u;
}

// ---------------- CSR build ----------------
__global__ __launch_bounds__(256) void k_count(const int* dst, int* deg){
    int i = blockIdx.x*256 + threadIdx.x;
    if (i < EE) atomicAdd(&deg[dst[i]], 1);
}

__global__ __launch_bounds__(256) void k_dinv(const int* deg, float* dinv){
    int n = blockIdx.x*256 + threadIdx.x;
    if (n < NN) dinv[n] = rsqrtf((float)deg[n] + 1.0f);
}

__global__ __launch_bounds__(1024) void k_scan(const int* cnt, int* rows){
    __shared__ int part[1024];
    int t = threadIdx.x;
    int base = t*20;
    int s = 0;
    for (int i = 0; i < 20; ++i){ int idx = base+i; if (idx < NN) s += cnt[idx]; }
    part[t] = s; __syncthreads();
    for (int off = 1; off < 1024; off <<= 1){
        int v = (t >= off) ? part[t-off] : 0;
        __syncthreads();
        part[t] += v;
        __syncthreads();
    }
    int run = part[t] - s;   // exclusive
    for (int i = 0; i < 20; ++i){
        int idx = base+i;
        if (idx < NN){ rows[idx] = run; run += cnt[idx]; }
    }
    if (t == 0) rows[NN] = EE;
}

__global__ __launch_bounds__(256) void k_fill(const int* src, const int* dst, const int* rows,
                                              int* cursor, int* col){
    int i = blockIdx.x*256 + threadIdx.x;
    if (i < EE){
        int d = dst[i];
        int pos = rows[d] + atomicAdd(&cursor[d], 1);
        col[pos] = src[i];
    }
}

// ---------------- fp32 GEMM  C[M x 128] = A[M x 128] @ W[128 x 128]  + epilogue ----------------
__global__ __launch_bounds__(512) void gemm128(const float* __restrict__ A, const float* __restrict__ Wm,
                                               float* __restrict__ C, int M,
                                               const float* srow, const float* bias,
                                               const float* resid, int relu){
    __shared__ __align__(16) float Ws[128*132];
    __shared__ float As[64*129];
    int tid = threadIdx.x;
    int r0 = blockIdx.x*64;
    for (int i = tid; i < 128*32; i += 512){
        int r = i >> 5, c4 = (i & 31) * 4;
        float4 v = ld4(Wm + r*128 + c4);
        st4(&Ws[r*132 + c4], v);
    }
    for (int i = tid; i < 64*32; i += 512){
        int r = i >> 5, c4 = (i & 31) * 4;
        float4 v = (r0 + r < M) ? ld4(A + (size_t)(r0+r)*128 + c4) : make_float4(0,0,0,0);
        As[r*129 + c4+0] = v.x; As[r*129 + c4+1] = v.y;
        As[r*129 + c4+2] = v.z; As[r*129 + c4+3] = v.w;
    }
    __syncthreads();
    int a = tid >> 5;
    int b = tid & 31;
    float acc[4][4] = {};
    #pragma unroll 4
    for (int d = 0; d < 128; ++d){
        float4 w = ld4(&Ws[d*132 + 4*b]);
        float wv[4] = {w.x, w.y, w.z, w.w};
        float av[4];
        #pragma unroll
        for (int i = 0; i < 4; ++i) av[i] = As[(4*a+i)*129 + d];
        #pragma unroll
        for (int i = 0; i < 4; ++i)
            #pragma unroll
            for (int j = 0; j < 4; ++j)
                acc[i][j] += av[i]*wv[j];
    }
    int cc = 4*b;
    #pragma unroll
    for (int i = 0; i < 4; ++i){
        int r = r0 + 4*a + i;
        if (r < M){
            float v[4];
            #pragma unroll
            for (int j = 0; j < 4; ++j) v[j] = acc[i][j];
            if (bias){
                #pragma unroll
                for (int j = 0; j < 4; ++j) v[j] += bias[cc+j];
            }
            if (relu){
                #pragma unroll
                for (int j = 0; j < 4; ++j) v[j] = fmaxf(v[j], 0.f);
            }
            if (resid){
                float4 rv = ld4(resid + (size_t)r*128 + cc);
                v[0]+=rv.x; v[1]+=rv.y; v[2]+=rv.z; v[3]+=rv.w;
            }
            if (srow){
                float sc = srow[r];
                #pragma unroll
                for (int j = 0; j < 4; ++j) v[j] *= sc;
            }
            st4(C + (size_t)r*128 + cc, make_float4(v[0],v[1],v[2],v[3]));
        }
    }
}

// ---------------- GCN aggregation ----------------
__global__ __launch_bounds__(256) void gcn_agg(const float* __restrict__ hp, const float* __restrict__ dinv,
                                               const int* __restrict__ rows, const int* __restrict__ col,
                                               const float* __restrict__ bias, float* __restrict__ out, int relu){
    int wid = (int)((blockIdx.x*256 + threadIdx.x) >> 6);
    int lane = threadIdx.x & 63;
    if (wid >= NN) return;
    int f = lane*2;
    float2 acc = ld2(hp + (size_t)wid*128 + f);
    int s = rows[wid], e = rows[wid+1];
    for (int j = s; j < e; ++j){
        int c = col[j];
        float2 v = ld2(hp + (size_t)c*128 + f);
        acc.x += v.x; acc.y += v.y;
    }
    float dn = dinv[wid];
    float ox = acc.x*dn + bias[f];
    float oy = acc.y*dn + bias[f+1];
    if (relu){ ox = fmaxf(ox, 0.f); oy = fmaxf(oy, 0.f); }
    *reinterpret_cast<float2*>(out + (size_t)wid*128 + f) = make_float2(ox, oy);
}

// ---------------- convert fp32 -> bf16 (same layout) ----------------
__global__ __launch_bounds__(256) void conv_bf16(const float* __restrict__ in, unsigned short* __restrict__ out, int n4){
    int i = blockIdx.x*256 + threadIdx.x;
    if (i < n4){
        float4 v = ld4(in + (size_t)i*4);
        ushort4 o;
        o.x = f2bf(v.x); o.y = f2bf(v.y); o.z = f2bf(v.z); o.w = f2bf(v.w);
        *reinterpret_cast<ushort4*>(out + (size_t)i*4) = o;
    }
}

// ---------------- convert + transpose: fp32 [M x 128] -> bf16 [128 x M] ----------------
__global__ __launch_bounds__(256) void conv_bf16_T(const float* __restrict__ in, unsigned short* __restrict__ out, int M){
    __shared__ float t[64][65];
    int r0 = blockIdx.x*64, c0 = blockIdx.y*64;
    int tid = threadIdx.x;
    for (int i = tid; i < 64*16; i += 256){
        int r = i >> 4, c4 = (i & 15) * 4;
        float4 v = (r0 + r < M) ? ld4(in + (size_t)(r0+r)*128 + c0 + c4) : make_float4(0,0,0,0);
        t[r][c4+0]=v.x; t[r][c4+1]=v.y; t[r][c4+2]=v.z; t[r][c4+3]=v.w;
    }
    __syncthreads();
    for (int i = tid; i < 64*16; i += 256){
        int c = i >> 4, r4 = (i & 15) * 4;
        if (r0 + r4 < M){
            ushort4 o;
            o.x = f2bf(t[r4+0][c]); o.y = f2bf(t[r4+1][c]);
            o.z = f2bf(t[r4+2][c]); o.w = f2bf(t[r4+3][c]);
            *reinterpret_cast<ushort4*>(out + (size_t)(c0+c)*M + r0 + r4) = o;
        }
    }
}

// ---------------- pass1: per-node softmax stats (MFMA, two-sweep) ----------------
// wave handles 16 n-rows; S[n][k] tiles via MFMA (A=K n-rows, B=Q k-rows -> C rows=n, cols=k)
__global__ __launch_bounds__(256) void attn_stats(const unsigned short* __restrict__ Kb,
                                                  const unsigned short* __restrict__ Qb2,
                                                  float* __restrict__ mo, float* __restrict__ zo){
    int tid = threadIdx.x;
    int wave = tid >> 6, lane = tid & 63;
    int l15 = lane & 15, q8 = (lane >> 4) * 8, quad = lane >> 4;
    int n0 = blockIdx.x*64 + wave*16;
    int row = n0 + l15;
    bool rv = row < NN;
    sh8 kf[4];
    #pragma unroll
    for (int s = 0; s < 4; ++s)
        kf[s] = rv ? *reinterpret_cast<const sh8*>(Kb + (size_t)row*128 + s*32 + q8) : (sh8)0;
    float mx[4] = {-1e30f,-1e30f,-1e30f,-1e30f};
    for (int kt = 0; kt < 125; ++kt){
        int k0 = kt*16;
        f32x4 sacc = (f32x4)0.f;
        #pragma unroll
        for (int s = 0; s < 4; ++s){
            sh8 qf = *reinterpret_cast<const sh8*>(Qb2 + (size_t)(k0 + l15)*128 + s*32 + q8);
            sacc = __builtin_amdgcn_mfma_f32_16x16x32_bf16(kf[s], qf, sacc, 0, 0, 0);
        }
        #pragma unroll
        for (int r = 0; r < 4; ++r) mx[r] = fmaxf(mx[r], sacc[r]);
    }
    #pragma unroll
    for (int r = 0; r < 4; ++r){
        #pragma unroll
        for (int m = 1; m < 16; m <<= 1) mx[r] = fmaxf(mx[r], __shfl_xor(mx[r], m));
    }
    float zs[4] = {0.f,0.f,0.f,0.f};
    for (int kt = 0; kt < 125; ++kt){
        int k0 = kt*16;
        f32x4 sacc = (f32x4)0.f;
        #pragma unroll
        for (int s = 0; s < 4; ++s){
            sh8 qf = *reinterpret_cast<const sh8*>(Qb2 + (size_t)(k0 + l15)*128 + s*32 + q8);
            sacc = __builtin_amdgcn_mfma_f32_16x16x32_bf16(kf[s], qf, sacc, 0, 0, 0);
        }
        #pragma unroll
        for (int r = 0; r < 4; ++r) zs[r] += __expf((sacc[r] - mx[r])*SCALE);
    }
    #pragma unroll
    for (int r = 0; r < 4; ++r){
        #pragma unroll
        for (int m = 1; m < 16; m <<= 1) zs[r] += __shfl_xor(zs[r], m);
    }
    if (l15 == 0){
        #pragma unroll
        for (int r = 0; r < 4; ++r){
            int n = n0 + quad*4 + r;
            if (n < NN){ mo[n] = mx[r]*SCALE; zo[n] = 1.f / zs[r]; }
        }
    }
}

// ---------------- pass2: attn partials: part[y][k][d] = sum_{n in slice} P[n][k] * V[n][d] ----------------
__global__ __launch_bounds__(256) void attn_av(const unsigned short* __restrict__ Kb,
                                               const unsigned short* __restrict__ Qb2,
                                               const unsigned short* __restrict__ Vt,
                                               const float* __restrict__ mo, const float* __restrict__ zo,
                                               float* __restrict__ part){
    __shared__ unsigned short Pt[64*72];
    __shared__ float msh[64], zsh[64];
    int tid = threadIdx.x;
    int wave = tid >> 6, lane = tid & 63;
    int l15 = lane & 15, q8 = (lane >> 4) * 8, quad = lane >> 4;
    int k0 = blockIdx.x*64;
    sh8 qf[4];
    {
        int krow = k0 + wave*16 + l15;
        bool kv = krow < KK;
        #pragma unroll
        for (int s = 0; s < 4; ++s)
            qf[s] = kv ? *reinterpret_cast<const sh8*>(Qb2 + (size_t)krow*128 + s*32 + q8) : (sh8)0;
    }
    f32x4 acc[4][2];
    #pragma unroll
    for (int g = 0; g < 4; ++g){ acc[g][0] = (f32x4)0.f; acc[g][1] = (f32x4)0.f; }
    for (int t = blockIdx.y; t < 313; t += PSPLIT){
        int n0 = t*64;
        if (tid < 64){
            int n = n0 + tid;
            msh[tid] = (n < NN) ? mo[n] : 0.f;
            zsh[tid] = (n < NN) ? zo[n] : 0.f;
        }
        __syncthreads();
        // S tiles: C[k(16 per wave)][n(64)]
        #pragma unroll
        for (int ns = 0; ns < 4; ++ns){
            f32x4 sacc = (f32x4)0.f;
            int nrow = n0 + ns*16 + l15;
            bool nv = nrow < NN;
            #pragma unroll
            for (int s = 0; s < 4; ++s){
                sh8 kf = nv ? *reinterpret_cast<const sh8*>(Kb + (size_t)nrow*128 + s*32 + q8) : (sh8)0;
                sacc = __builtin_amdgcn_mfma_f32_16x16x32_bf16(qf[s], kf, sacc, 0, 0, 0);
            }
            float mm = msh[ns*16 + l15];
            float zz = zsh[ns*16 + l15];
            #pragma unroll
            for (int r = 0; r < 4; ++r){
                float p = __expf(sacc[r]*SCALE - mm) * zz;
                Pt[(wave*16 + quad*4 + r)*72 + ns*16 + l15] = f2bf(p);
            }
        }
        __syncthreads();
        // PV: out[k(64)][d(32 per wave)] over n-chunk of 64
        #pragma unroll
        for (int t2 = 0; t2 < 2; ++t2){
            sh8 bf0 = *reinterpret_cast<const sh8*>(Vt + (size_t)(wave*32 + l15)*NN + n0 + t2*32 + q8);
            sh8 bf1 = *reinterpret_cast<const sh8*>(Vt + (size_t)(wave*32 + 16 + l15)*NN + n0 + t2*32 + q8);
            #pragma unroll
            for (int g = 0; g < 4; ++g){
                sh8 af = *reinterpret_cast<const sh8*>(&Pt[(g*16 + l15)*72 + t2*32 + q8]);
                acc[g][0] = __builtin_amdgcn_mfma_f32_16x16x32_bf16(af, bf0, acc[g][0], 0, 0, 0);
                acc[g][1] = __builtin_amdgcn_mfma_f32_16x16x32_bf16(af, bf1, acc[g][1], 0, 0, 0);
            }
        }
        __syncthreads();
    }
    float* pbase = part + (size_t)blockIdx.y*KK*128;
    #pragma unroll
    for (int g = 0; g < 4; ++g){
        #pragma unroll
        for (int ds = 0; ds < 2; ++ds){
            #pragma unroll
            for (int r = 0; r < 4; ++r){
                int k = k0 + g*16 + quad*4 + r;
                if (k < KK) pbase[(size_t)k*128 + wave*32 + ds*16 + l15] = acc[g][ds][r];
            }
        }
    }
}

// ---------------- pass3: xout[n][d] = sum_k P[n][k] * xl[k][d] ----------------
__global__ __launch_bounds__(256) void attn_xout(const unsigned short* __restrict__ Kb,
                                                 const unsigned short* __restrict__ Qb2,
                                                 const unsigned short* __restrict__ xlt,
                                                 const float* __restrict__ mo, const float* __restrict__ zo,
                                                 float* __restrict__ xout){
    __shared__ unsigned short Pt[64*72];
    int tid = threadIdx.x;
    int wave = tid >> 6, lane = tid & 63;
    int l15 = lane & 15, q8 = (lane >> 4) * 8, quad = lane >> 4;
    int n0 = blockIdx.x*64;
    sh8 kf[4];
    {
        int nrow = n0 + wave*16 + l15;
        bool nv = nrow < NN;
        #pragma unroll
        for (int s = 0; s < 4; ++s)
            kf[s] = nv ? *reinterpret_cast<const sh8*>(Kb + (size_t)nrow*128 + s*32 + q8) : (sh8)0;
    }
    float mr[4], zr[4];
    #pragma unroll
    for (int r = 0; r < 4; ++r){
        int n = n0 + wave*16 + quad*4 + r;
        mr[r] = (n < NN) ? mo[n] : 0.f;
        zr[r] = (n < NN) ? zo[n] : 0.f;
    }
    f32x4 acc[4][2];
    #pragma unroll
    for (int g = 0; g < 4; ++g){ acc[g][0] = (f32x4)0.f; acc[g][1] = (f32x4)0.f; }
    for (int kt = 0; kt < 32; ++kt){
        int k0 = kt*64;
        __syncthreads();
        // S tiles: C[n(16 per wave)][k(64)]
        #pragma unroll
        for (int ks = 0; ks < 4; ++ks){
            f32x4 sacc = (f32x4)0.f;
            int krow = k0 + ks*16 + l15;
            bool kv = krow < KK;
            #pragma unroll
            for (int s = 0; s < 4; ++s){
                sh8 qfr = kv ? *reinterpret_cast<const sh8*>(Qb2 + (size_t)krow*128 + s*32 + q8) : (sh8)0;
                sacc = __builtin_amdgcn_mfma_f32_16x16x32_bf16(kf[s], qfr, sacc, 0, 0, 0);
            }
            #pragma unroll
            for (int r = 0; r < 4; ++r){
                float p = kv ? (__expf(sacc[r]*SCALE - mr[r]) * zr[r]) : 0.f;
                Pt[(wave*16 + quad*4 + r)*72 + ks*16 + l15] = f2bf(p);
            }
        }
        __syncthreads();
        // PV: out[n(64)][d(32 per wave)] over k-chunk of 64
        #pragma unroll
        for (int t2 = 0; t2 < 2; ++t2){
            sh8 bf0 = *reinterpret_cast<const sh8*>(xlt + (size_t)(wave*32 + l15)*KK + k0 + t2*32 + q8);
            sh8 bf1 = *reinterpret_cast<const sh8*>(xlt + (size_t)(wave*32 + 16 + l15)*KK + k0 + t2*32 + q8);
            #pragma unroll
            for (int g = 0; g < 4; ++g){
                sh8 af = *reinterpret_cast<const sh8*>(&Pt[(g*16 + l15)*72 + t2*32 + q8]);
                acc[g][0] = __builtin_amdgcn_mfma_f32_16x16x32_bf16(af, bf0, acc[g][0], 0, 0, 0);
                acc[g][1] = __builtin_amdgcn_mfma_f32_16x16x32_bf16(af, bf1, acc[g][1], 0, 0, 0);
            }
        }
    }
    #pragma unroll
    for (int g = 0; g < 4; ++g){
        #pragma unroll
        for (int ds = 0; ds < 2; ++ds){
            #pragma unroll
            for (int r = 0; r < 4; ++r){
                int n = n0 + g*16 + quad*4 + r;
                if (n < NN) xout[(size_t)n*128 + wave*32 + ds*16 + l15] = acc[g][ds][r];
            }
        }
    }
}

// ---------------- LayerNorm over D=128 (with optional partial-sum input) ----------------
__global__ __launch_bounds__(128) void ln_ker(const float* __restrict__ in, int nparts,
                                              const float* __restrict__ resid,
                                              const float* __restrict__ g, const float* __restrict__ be,
                                              float* __restrict__ out){
    __shared__ float rs[128], rq[128];
    int r = blockIdx.x, t = threadIdx.x;
    float v = 0.f;
    for (int p = 0; p < nparts; ++p) v += in[(size_t)p*KK*128 + r*128 + t];
    if (resid) v += resid[r*128 + t];
    rs[t] = v; rq[t] = v*v;
    __syncthreads();
    for (int off = 64; off > 0; off >>= 1){
        if (t < off){ rs[t] += rs[t+off]; rq[t] += rq[t+off]; }
        __syncthreads();
    }
    float mean = rs[0]*(1.f/128.f);
    float var = rq[0]*(1.f/128.f) - mean*mean;
    out[r*128 + t] = (v - mean)*rsqrtf(var + 1e-5f)*g[t] + be[t];
}

// ---------------- launcher ----------------
extern "C" void kernel_launch(void* const* d_in, const int* in_sizes, int n_in,
                              void* d_out, int out_size, void* d_ws, size_t ws_size,
                              hipStream_t stream){
    cfp x  = (cfp)d_in[0];
    const int* ei = (const int*)d_in[1];
    const int* esrc = ei;
    const int* edst = ei + EE;
    cfp W1=(cfp)d_in[3], b1=(cfp)d_in[4], W2=(cfp)d_in[5], b2=(cfp)d_in[6];
    cfp S =(cfp)d_in[7];
    cfp Wq=(cfp)d_in[8],  bq=(cfp)d_in[9],  Wk=(cfp)d_in[10], bk=(cfp)d_in[11];
    cfp Wv=(cfp)d_in[12], bv=(cfp)d_in[13], Wo=(cfp)d_in[14], bo=(cfp)d_in[15];
    cfp g0=(cfp)d_in[16], be0=(cfp)d_in[17], g1=(cfp)d_in[18], be1=(cfp)d_in[19];
    cfp Wl=(cfp)d_in[20], bl=(cfp)d_in[21], W3=(cfp)d_in[22], b3=(cfp)d_in[23];
    cfp W4=(cfp)d_in[24], b4=(cfp)d_in[25], W5=(cfp)d_in[26], b5=(cfp)d_in[27];

    char* wsb = (char*)d_ws;
    const size_t MB = 1048576;
    int*   deg    = (int*)  (wsb + 0);
    float* dinv   = (float*)(wsb + 81920);
    int*   rows   = (int*)  (wsb + 163840);
    int*   cursor = (int*)  (wsb + 245760);
    int*   col    = (int*)  (wsb + 327680);
    float* Qb     = (float*)(wsb + 2*MB);
    float* part   = (float*)(wsb + 4*MB);    // PSPLIT x KK x 128 fp32 = 16.4 MB
    float* o1     = (float*)(wsb + 21*MB);
    float* o2     = (float*)(wsb + 22*MB);
    float* o3     = (float*)(wsb + 23*MB);
    float* xlb    = (float*)(wsb + 24*MB);
    float* mbuf   = (float*)(wsb + 25*MB);
    float* zinv   = (float*)(wsb + 26*MB);
    unsigned short* Kbf = (unsigned short*)(wsb + 27*MB);
    unsigned short* Qbf = (unsigned short*)(wsb + 33*MB);
    unsigned short* Vt  = (unsigned short*)(wsb + 34*MB);
    unsigned short* xlt = (unsigned short*)(wsb + 40*MB);
    float* NB0    = (float*)(wsb + 41*MB);
    float* NB1    = (float*)(wsb + 52*MB);
    float* NB2    = (float*)(wsb + 63*MB);
    float* NB3    = (float*)(wsb + 74*MB);
    float* outp   = (float*)d_out;

    (void)hipMemsetAsync(deg, 0, NN*sizeof(int), stream);
    (void)hipMemsetAsync(cursor, 0, NN*sizeof(int), stream);

    // CSR build
    k_count<<<1250, 256, 0, stream>>>(edst, deg);
    k_dinv<<<79, 256, 0, stream>>>(deg, dinv);
    k_scan<<<1, 1024, 0, stream>>>(deg, rows);
    k_fill<<<1250, 256, 0, stream>>>(esrc, edst, rows, cursor, col);

    const int GN = 313;   // ceil(NN/64)
    const int GK = 32;    // ceil(KK/64)

    // GCN1: h1 = relu(agg(x@W1 * dinv) * dinv + b1)
    gemm128<<<GN, 512, 0, stream>>>(x, W1, NB0, NN, dinv, nullptr, nullptr, 0);
    gcn_agg<<<5000, 256, 0, stream>>>(NB0, dinv, rows, col, b1, NB1, 1);
    // GCN2 -> h2 in NB2
    gemm128<<<GN, 512, 0, stream>>>(NB1, W2, NB0, NN, dinv, nullptr, nullptr, 0);
    gcn_agg<<<5000, 256, 0, stream>>>(NB0, dinv, rows, col, b2, NB2, 1);
    // Kd = gcn(h2, Wk, bk) -> NB1 -> Kbf
    gemm128<<<GN, 512, 0, stream>>>(NB2, Wk, NB0, NN, dinv, nullptr, nullptr, 0);
    gcn_agg<<<5000, 256, 0, stream>>>(NB0, dinv, rows, col, bk, NB1, 0);
    conv_bf16<<<2500, 256, 0, stream>>>(NB1, Kbf, NN*32);
    // Vd = gcn(h2, Wv, bv) -> NB3 -> Vt (transposed bf16)
    gemm128<<<GN, 512, 0, stream>>>(NB2, Wv, NB0, NN, dinv, nullptr, nullptr, 0);
    gcn_agg<<<5000, 256, 0, stream>>>(NB0, dinv, rows, col, bv, NB3, 0);
    conv_bf16_T<<<dim3(GN, 2), 256, 0, stream>>>(NB3, Vt, NN);
    // Q = S@Wq + bq -> Qb -> Qbf
    gemm128<<<GK, 512, 0, stream>>>(S, Wq, Qb, KK, nullptr, bq, nullptr, 0);
    conv_bf16<<<250, 256, 0, stream>>>(Qb, Qbf, KK*32);
    // softmax stats over seed dim
    attn_stats<<<GN, 256, 0, stream>>>(Kbf, Qbf, mbuf, zinv);
    // attn partials
    attn_av<<<dim3(GK, PSPLIT), 256, 0, stream>>>(Kbf, Qbf, Vt, mbuf, zinv, part);
    // out = LN(sum(part) + Q)
    ln_ker<<<KK, 128, 0, stream>>>(part, PSPLIT, Qb, g0, be0, o1);
    // o2 = o1 + relu(o1@Wo + bo)
    gemm128<<<GK, 512, 0, stream>>>(o1, Wo, o2, KK, nullptr, bo, o1, 1);
    ln_ker<<<KK, 128, 0, stream>>>(o2, 1, nullptr, g1, be1, o3);
    // xl = o3@Wl + bl -> xlb -> xlt (transposed bf16)
    gemm128<<<GK, 512, 0, stream>>>(o3, Wl, xlb, KK, nullptr, bl, nullptr, 0);
    conv_bf16_T<<<dim3(GK, 2), 256, 0, stream>>>(xlb, xlt, KK);
    // x_out[n][d] = sum_k P[n][k] * xl[k][d]
    attn_xout<<<GN, 256, 0, stream>>>(Kbf, Qbf, xlt, mbuf, zinv, NB0);
    // GCN3
    gemm128<<<GN, 512, 0, stream>>>(NB0, W3, NB1, NN, dinv, nullptr, nullptr, 0);
    gcn_agg<<<5000, 256, 0, stream>>>(NB1, dinv, rows, col, b3, NB2, 1);
    // GCN4
    gemm128<<<GN, 512, 0, stream>>>(NB2, W4, NB0, NN, dinv, nullptr, nullptr, 0);
    gcn_agg<<<5000, 256, 0, stream>>>(NB0, dinv, rows, col, b4, NB1, 1);
    // GCN5 -> d_out
    gemm128<<<GN, 512, 0, stream>>>(NB1, W5, NB0, NN, dinv, nullptr, nullptr, 0);
    gcn_agg<<<5000, 256, 0, stream>>>(NB0, dinv, rows, col, b5, outp, 0);
}

// Round 5
// 893.805 us; speedup vs baseline: 1.2820x; 1.2820x over previous
//
#include <hip/hip_runtime.h>

#define NN 20000
#define EE 320000
#define KK 2000
#define KP 2048          // padded K-dim of E (zeros in 2000..2047)
#define SCALE 0.08838834764831845f

typedef const float* cfp;
typedef __attribute__((ext_vector_type(8))) short sh8;
typedef __attribute__((ext_vector_type(4))) float f32x4;

static __device__ __forceinline__ float4 ld4(const float* p){ return *reinterpret_cast<const float4*>(p); }
static __device__ __forceinline__ float2 ld2(const float* p){ return *reinterpret_cast<const float2*>(p); }
static __device__ __forceinline__ void st4(float* p, float4 v){ *reinterpret_cast<float4*>(p) = v; }

static __device__ __forceinline__ unsigned short f2bf(float f){
    unsigned int u = __float_as_uint(f);
    u = (u + 0x7FFFu + ((u >> 16) & 1u)) >> 16;
    return (unsigned short)u;
}
static __device__ __forceinline__ float bf2f(unsigned short h){
    return __uint_as_float(((unsigned int)h) << 16);
}

// ---------------- CSR build ----------------
__global__ __launch_bounds__(256) void k_count(const int* dst, int* deg){
    int i = blockIdx.x*256 + threadIdx.x;
    if (i < EE) atomicAdd(&deg[dst[i]], 1);
}

__global__ __launch_bounds__(256) void k_dinv(const int* deg, float* dinv){
    int n = blockIdx.x*256 + threadIdx.x;
    if (n < NN) dinv[n] = rsqrtf((float)deg[n] + 1.0f);
}

__global__ __launch_bounds__(1024) void k_scan(const int* cnt, int* rows){
    __shared__ int part[1024];
    int t = threadIdx.x;
    int base = t*20;
    int s = 0;
    for (int i = 0; i < 20; ++i){ int idx = base+i; if (idx < NN) s += cnt[idx]; }
    part[t] = s; __syncthreads();
    for (int off = 1; off < 1024; off <<= 1){
        int v = (t >= off) ? part[t-off] : 0;
        __syncthreads();
        part[t] += v;
        __syncthreads();
    }
    int run = part[t] - s;   // exclusive
    for (int i = 0; i < 20; ++i){
        int idx = base+i;
        if (idx < NN){ rows[idx] = run; run += cnt[idx]; }
    }
    if (t == 0) rows[NN] = EE;
}

__global__ __launch_bounds__(256) void k_fill(const int* src, const int* dst, const int* rows,
                                              int* cursor, int* col){
    int i = blockIdx.x*256 + threadIdx.x;
    if (i < EE){
        int d = dst[i];
        int pos = rows[d] + atomicAdd(&cursor[d], 1);
        col[pos] = src[i];
    }
}

// ---------------- fp32 GEMM  C[M x 128] = A[M x 128] @ W[128 x 128]  + epilogue ----------------
__global__ __launch_bounds__(512) void gemm128(const float* __restrict__ A, const float* __restrict__ Wm,
                                               float* __restrict__ C, int M,
                                               const float* srow, const float* bias,
                                               const float* resid, int relu){
    __shared__ __align__(16) float Ws[128*132];
    __shared__ float As[64*129];
    int tid = threadIdx.x;
    int r0 = blockIdx.x*64;
    for (int i = tid; i < 128*32; i += 512){
        int r = i >> 5, c4 = (i & 31) * 4;
        float4 v = ld4(Wm + r*128 + c4);
        st4(&Ws[r*132 + c4], v);
    }
    for (int i = tid; i < 64*32; i += 512){
        int r = i >> 5, c4 = (i & 31) * 4;
        float4 v = (r0 + r < M) ? ld4(A + (size_t)(r0+r)*128 + c4) : make_float4(0,0,0,0);
        As[r*129 + c4+0] = v.x; As[r*129 + c4+1] = v.y;
        As[r*129 + c4+2] = v.z; As[r*129 + c4+3] = v.w;
    }
    __syncthreads();
    int a = tid >> 5;
    int b = tid & 31;
    float acc[4][4] = {};
    #pragma unroll 4
    for (int d = 0; d < 128; ++d){
        float4 w = ld4(&Ws[d*132 + 4*b]);
        float wv[4] = {w.x, w.y, w.z, w.w};
        float av[4];
        #pragma unroll
        for (int i = 0; i < 4; ++i) av[i] = As[(4*a+i)*129 + d];
        #pragma unroll
        for (int i = 0; i < 4; ++i)
            #pragma unroll
            for (int j = 0; j < 4; ++j)
                acc[i][j] += av[i]*wv[j];
    }
    int cc = 4*b;
    #pragma unroll
    for (int i = 0; i < 4; ++i){
        int r = r0 + 4*a + i;
        if (r < M){
            float v[4];
            #pragma unroll
            for (int j = 0; j < 4; ++j) v[j] = acc[i][j];
            if (bias){
                #pragma unroll
                for (int j = 0; j < 4; ++j) v[j] += bias[cc+j];
            }
            if (relu){
                #pragma unroll
                for (int j = 0; j < 4; ++j) v[j] = fmaxf(v[j], 0.f);
            }
            if (resid){
                float4 rv = ld4(resid + (size_t)r*128 + cc);
                v[0]+=rv.x; v[1]+=rv.y; v[2]+=rv.z; v[3]+=rv.w;
            }
            if (srow){
                float sc = srow[r];
                #pragma unroll
                for (int j = 0; j < 4; ++j) v[j] *= sc;
            }
            st4(C + (size_t)r*128 + cc, make_float4(v[0],v[1],v[2],v[3]));
        }
    }
}

// ---------------- GCN aggregation ----------------
__global__ __launch_bounds__(256) void gcn_agg(const float* __restrict__ hp, const float* __restrict__ dinv,
                                               const int* __restrict__ rows, const int* __restrict__ col,
                                               const float* __restrict__ bias, float* __restrict__ out, int relu){
    int wid = (int)((blockIdx.x*256 + threadIdx.x) >> 6);
    int lane = threadIdx.x & 63;
    if (wid >= NN) return;
    int f = lane*2;
    float2 acc = ld2(hp + (size_t)wid*128 + f);
    int s = rows[wid], e = rows[wid+1];
    for (int j = s; j < e; ++j){
        int c = col[j];
        float2 v = ld2(hp + (size_t)c*128 + f);
        acc.x += v.x; acc.y += v.y;
    }
    float dn = dinv[wid];
    float ox = acc.x*dn + bias[f];
    float oy = acc.y*dn + bias[f+1];
    if (relu){ ox = fmaxf(ox, 0.f); oy = fmaxf(oy, 0.f); }
    *reinterpret_cast<float2*>(out + (size_t)wid*128 + f) = make_float2(ox, oy);
}

// ---------------- convert fp32 -> bf16 (same layout) ----------------
__global__ __launch_bounds__(256) void conv_bf16(const float* __restrict__ in, unsigned short* __restrict__ out, int n4){
    int i = blockIdx.x*256 + threadIdx.x;
    if (i < n4){
        float4 v = ld4(in + (size_t)i*4);
        ushort4 o;
        o.x = f2bf(v.x); o.y = f2bf(v.y); o.z = f2bf(v.z); o.w = f2bf(v.w);
        *reinterpret_cast<ushort4*>(out + (size_t)i*4) = o;
    }
}

// ---------------- convert + transpose (+ optional per-source-row scale): fp32 [M x 128] -> bf16 [128 x ldout] ----------------
__global__ __launch_bounds__(256) void conv_bf16_T(const float* __restrict__ in, unsigned short* __restrict__ out,
                                                   int M, int ldout, const float* __restrict__ rscale){
    __shared__ float t[64][65];
    int r0 = blockIdx.x*64, c0 = blockIdx.y*64;
    int tid = threadIdx.x;
    for (int i = tid; i < 64*16; i += 256){
        int r = i >> 4, c4 = (i & 15) * 4;
        float4 v = (r0 + r < M) ? ld4(in + (size_t)(r0+r)*128 + c0 + c4) : make_float4(0,0,0,0);
        if (rscale && r0 + r < M){
            float sc = rscale[r0 + r];
            v.x *= sc; v.y *= sc; v.z *= sc; v.w *= sc;
        }
        t[r][c4+0]=v.x; t[r][c4+1]=v.y; t[r][c4+2]=v.z; t[r][c4+3]=v.w;
    }
    __syncthreads();
    for (int i = tid; i < 64*16; i += 256){
        int c = i >> 4, r4 = (i & 15) * 4;
        if (r0 + r4 < M){
            ushort4 o;
            o.x = f2bf(t[r4+0][c]); o.y = f2bf(t[r4+1][c]);
            o.z = f2bf(t[r4+2][c]); o.w = f2bf(t[r4+3][c]);
            *reinterpret_cast<ushort4*>(out + (size_t)(c0+c)*ldout + r0 + r4) = o;
        }
    }
}

__global__ __launch_bounds__(256) void k_rcp(const float* __restrict__ z, float* __restrict__ zinv){
    int n = blockIdx.x*256 + threadIdx.x;
    if (n < NN) zinv[n] = 1.f / z[n];
}

static __device__ __forceinline__ sh8 ldfrag(const unsigned short* base, int row, int lim, int ld, int off){
    if (row < lim) return *reinterpret_cast<const sh8*>(base + (size_t)row*ld + off);
    sh8 z = (sh8)0;
    return z;
}

// ---------------- S-GEMM + exp + z-sum: E[n][k] = exp(SCALE * Kd[n].Q[k]), z[n] += row-sum ----------------
// E is [NN x KP] bf16, cols >= KK zero-filled. atomicAdd partial row sums into z.
__global__ __launch_bounds__(256) void s_gemm_exp(const unsigned short* __restrict__ Kb,
                                                  const unsigned short* __restrict__ Qb2,
                                                  unsigned short* __restrict__ E, float* __restrict__ z){
    __shared__ unsigned short Es[64*68];
    int tid = threadIdx.x;
    int wave = tid >> 6, lane = tid & 63;
    int wm = wave >> 1, wn = wave & 1;
    int n_blk = blockIdx.x*64, k_blk = blockIdx.y*64;
    int m_base = n_blk + wm*32;
    int k_base = k_blk + wn*32;
    int l15 = lane & 15;
    int roff = (lane >> 4) * 8;
    int rA0 = m_base + l15, rA1 = rA0 + 16;
    int rB0 = k_base + l15, rB1 = rB0 + 16;
    f32x4 acc00 = (f32x4)0.f, acc01 = (f32x4)0.f, acc10 = (f32x4)0.f, acc11 = (f32x4)0.f;
    for (int r = 0; r < 128; r += 32){
        sh8 a0 = ldfrag(Kb, rA0, NN, 128, r + roff);
        sh8 a1 = ldfrag(Kb, rA1, NN, 128, r + roff);
        sh8 b0 = ldfrag(Qb2, rB0, KK, 128, r + roff);
        sh8 b1 = ldfrag(Qb2, rB1, KK, 128, r + roff);
        acc00 = __builtin_amdgcn_mfma_f32_16x16x32_bf16(a0, b0, acc00, 0, 0, 0);
        acc01 = __builtin_amdgcn_mfma_f32_16x16x32_bf16(a0, b1, acc01, 0, 0, 0);
        acc10 = __builtin_amdgcn_mfma_f32_16x16x32_bf16(a1, b0, acc10, 0, 0, 0);
        acc11 = __builtin_amdgcn_mfma_f32_16x16x32_bf16(a1, b1, acc11, 0, 0, 0);
    }
    int rq = (lane >> 4) * 4;
    f32x4 accs[2][2] = {{acc00, acc01},{acc10, acc11}};
    #pragma unroll
    for (int mi = 0; mi < 2; ++mi){
        #pragma unroll
        for (int ni = 0; ni < 2; ++ni){
            f32x4 a = accs[mi][ni];
            int c_loc = wn*32 + ni*16 + l15;
            bool kv = (k_blk + c_loc) < KK;
            #pragma unroll
            for (int reg = 0; reg < 4; ++reg){
                int r_loc = wm*32 + mi*16 + rq + reg;
                float e = kv ? __expf(a[reg]*SCALE) : 0.f;
                Es[r_loc*68 + c_loc] = f2bf(e);
            }
        }
    }
    __syncthreads();
    // per-row partial z
    if (tid < 64){
        int n = n_blk + tid;
        if (n < NN){
            float s = 0.f;
            #pragma unroll 8
            for (int j = 0; j < 64; ++j) s += bf2f(Es[tid*68 + j]);
            atomicAdd(&z[n], s);
        }
    }
    // coalesced store (16B chunks); cols >= KK store zeros (pad region of E)
    for (int i = tid; i < 512; i += 256){
        int r = i >> 3, c8 = (i & 7) * 8;
        if (n_blk + r < NN){
            ushort4 lo = *reinterpret_cast<const ushort4*>(&Es[r*68 + c8]);
            ushort4 hi = *reinterpret_cast<const ushort4*>(&Es[r*68 + c8 + 4]);
            unsigned short* dst = E + (size_t)(n_blk + r)*KP + k_blk + c8;
            *reinterpret_cast<ushort4*>(dst) = lo;
            *reinterpret_cast<ushort4*>(dst + 4) = hi;
        }
    }
}

// ---------------- attn GEMM: attn[kk][d] += sum_n E[n][kk] * Vtz[d][n]  (TN, LDS-staged A) ----------------
#define ACHUNKS 625          // 20000 / 32
#define ZSPLIT 32
__global__ __launch_bounds__(256) void attn_gemm(const unsigned short* __restrict__ E,
                                                 const unsigned short* __restrict__ Vt,
                                                 float* __restrict__ attn){
    __shared__ unsigned short As[64*36];
    int tid = threadIdx.x;
    int wave = tid >> 6, lane = tid & 63;
    int kk0 = blockIdx.x*64;
    int per = (ACHUNKS + ZSPLIT - 1) / ZSPLIT;      // 20
    int c0 = blockIdx.y*per;
    int c1 = min(ACHUNKS, c0 + per);
    int l15 = lane & 15;
    int q8 = (lane >> 4) * 8;
    int d0 = wave*32;
    int n_l = tid & 31;
    int k8 = (tid >> 5) * 8;
    f32x4 acc[4][2];
    #pragma unroll
    for (int g = 0; g < 4; ++g){ acc[g][0] = (f32x4)0.f; acc[g][1] = (f32x4)0.f; }
    for (int ch = c0; ch < c1; ++ch){
        int r0 = ch*32;
        // stage E[r0..r0+31][kk0..kk0+63] transposed into As[k][n] (ld 36)
        {
            const unsigned short* prow = E + (size_t)(r0 + n_l)*KP + kk0 + k8;
            unsigned short tmp[8];
            *reinterpret_cast<sh8*>(tmp) = *reinterpret_cast<const sh8*>(prow);
            #pragma unroll
            for (int j = 0; j < 8; ++j) As[(k8 + j)*36 + n_l] = tmp[j];
        }
        __syncthreads();
        // B fragments direct from Vtz (contiguous in n)
        const unsigned short* vb = Vt + (size_t)(d0 + l15)*NN + r0 + q8;
        sh8 b0 = *reinterpret_cast<const sh8*>(vb);
        sh8 b1 = *reinterpret_cast<const sh8*>(vb + (size_t)16*NN);
        #pragma unroll
        for (int g = 0; g < 4; ++g){
            const unsigned short* ap = &As[(g*16 + l15)*36 + q8];
            union { struct { ushort4 lo, hi; } u; sh8 v; } af;
            af.u.lo = *reinterpret_cast<const ushort4*>(ap);
            af.u.hi = *reinterpret_cast<const ushort4*>(ap + 4);
            acc[g][0] = __builtin_amdgcn_mfma_f32_16x16x32_bf16(af.v, b0, acc[g][0], 0, 0, 0);
            acc[g][1] = __builtin_amdgcn_mfma_f32_16x16x32_bf16(af.v, b1, acc[g][1], 0, 0, 0);
        }
        __syncthreads();
    }
    int rq = (lane >> 4) * 4;
    #pragma unroll
    for (int g = 0; g < 4; ++g){
        #pragma unroll
        for (int ni = 0; ni < 2; ++ni){
            int d = d0 + ni*16 + l15;
            #pragma unroll
            for (int reg = 0; reg < 4; ++reg){
                int kk = kk0 + g*16 + rq + reg;
                if (kk < KK) atomicAdd(&attn[(size_t)kk*128 + d], acc[g][ni][reg]);
            }
        }
    }
}

// ---------------- NT MFMA GEMM with per-row scale: C[m][n] = rscale[m] * sum_r A[m][r]*B[n][r] ----------------
__global__ __launch_bounds__(256) void gemm_nt_scale(const unsigned short* __restrict__ A, int ldA, int M,
                                                     const unsigned short* __restrict__ B, int ldB, int Ncols,
                                                     int R, float* __restrict__ C, int ldC,
                                                     const float* __restrict__ rscale){
    int tid = threadIdx.x;
    int wave = tid >> 6, lane = tid & 63;
    int wm = wave >> 1, wn = wave & 1;
    int m_base = blockIdx.x*64 + wm*32;
    int n_base = blockIdx.y*64 + wn*32;
    int l15 = lane & 15;
    int roff = (lane >> 4) * 8;
    int rA0 = m_base + l15, rA1 = rA0 + 16;
    int rB0 = n_base + l15, rB1 = rB0 + 16;
    f32x4 acc00 = (f32x4)0.f, acc01 = (f32x4)0.f, acc10 = (f32x4)0.f, acc11 = (f32x4)0.f;
    for (int r = 0; r < R; r += 32){
        sh8 a0 = ldfrag(A, rA0, M, ldA, r + roff);
        sh8 a1 = ldfrag(A, rA1, M, ldA, r + roff);
        sh8 b0 = ldfrag(B, rB0, Ncols, ldB, r + roff);
        sh8 b1 = ldfrag(B, rB1, Ncols, ldB, r + roff);
        acc00 = __builtin_amdgcn_mfma_f32_16x16x32_bf16(a0, b0, acc00, 0, 0, 0);
        acc01 = __builtin_amdgcn_mfma_f32_16x16x32_bf16(a0, b1, acc01, 0, 0, 0);
        acc10 = __builtin_amdgcn_mfma_f32_16x16x32_bf16(a1, b0, acc10, 0, 0, 0);
        acc11 = __builtin_amdgcn_mfma_f32_16x16x32_bf16(a1, b1, acc11, 0, 0, 0);
    }
    int rq = (lane >> 4) * 4;
    f32x4 accs[2][2] = {{acc00, acc01},{acc10, acc11}};
    #pragma unroll
    for (int mi = 0; mi < 2; ++mi){
        #pragma unroll
        for (int ni = 0; ni < 2; ++ni){
            f32x4 a = accs[mi][ni];
            int gn = n_base + ni*16 + l15;
            if (gn >= Ncols) continue;
            #pragma unroll
            for (int reg = 0; reg < 4; ++reg){
                int gm = m_base + mi*16 + rq + reg;
                if (gm < M){
                    float v = a[reg];
                    if (rscale) v *= rscale[gm];
                    C[(size_t)gm*ldC + gn] = v;
                }
            }
        }
    }
}

// ---------------- LayerNorm over D=128 ----------------
__global__ __launch_bounds__(128) void ln_ker(const float* __restrict__ in, const float* __restrict__ resid,
                                              const float* __restrict__ g, const float* __restrict__ be,
                                              float* __restrict__ out){
    __shared__ float rs[128], rq[128];
    int r = blockIdx.x, t = threadIdx.x;
    float v = in[r*128 + t];
    if (resid) v += resid[r*128 + t];
    rs[t] = v; rq[t] = v*v;
    __syncthreads();
    for (int off = 64; off > 0; off >>= 1){
        if (t < off){ rs[t] += rs[t+off]; rq[t] += rq[t+off]; }
        __syncthreads();
    }
    float mean = rs[0]*(1.f/128.f);
    float var = rq[0]*(1.f/128.f) - mean*mean;
    out[r*128 + t] = (v - mean)*rsqrtf(var + 1e-5f)*g[t] + be[t];
}

// ---------------- launcher ----------------
extern "C" void kernel_launch(void* const* d_in, const int* in_sizes, int n_in,
                              void* d_out, int out_size, void* d_ws, size_t ws_size,
                              hipStream_t stream){
    cfp x  = (cfp)d_in[0];
    const int* ei = (const int*)d_in[1];
    const int* esrc = ei;
    const int* edst = ei + EE;
    cfp W1=(cfp)d_in[3], b1=(cfp)d_in[4], W2=(cfp)d_in[5], b2=(cfp)d_in[6];
    cfp S =(cfp)d_in[7];
    cfp Wq=(cfp)d_in[8],  bq=(cfp)d_in[9],  Wk=(cfp)d_in[10], bk=(cfp)d_in[11];
    cfp Wv=(cfp)d_in[12], bv=(cfp)d_in[13], Wo=(cfp)d_in[14], bo=(cfp)d_in[15];
    cfp g0=(cfp)d_in[16], be0=(cfp)d_in[17], g1=(cfp)d_in[18], be1=(cfp)d_in[19];
    cfp Wl=(cfp)d_in[20], bl=(cfp)d_in[21], W3=(cfp)d_in[22], b3=(cfp)d_in[23];
    cfp W4=(cfp)d_in[24], b4=(cfp)d_in[25], W5=(cfp)d_in[26], b5=(cfp)d_in[27];

    char* wsb = (char*)d_ws;
    const size_t MB = 1048576;
    int*   deg    = (int*)  (wsb + 0);
    float* dinv   = (float*)(wsb + 81920);
    int*   rows   = (int*)  (wsb + 163840);
    int*   cursor = (int*)  (wsb + 245760);
    int*   col    = (int*)  (wsb + 327680);
    float* Qb     = (float*)(wsb + 2*MB);
    float* attn   = (float*)(wsb + 3*MB);
    float* o1     = (float*)(wsb + 4*MB);
    float* o2     = (float*)(wsb + 5*MB);
    float* o3     = (float*)(wsb + 6*MB);
    float* xlb    = (float*)(wsb + 7*MB);
    float* zbuf   = (float*)(wsb + 8*MB);
    float* zinv   = (float*)(wsb + 8*MB + 131072);
    unsigned short* Kbf = (unsigned short*)(wsb + 9*MB);
    unsigned short* Qbf = (unsigned short*)(wsb + 15*MB);
    unsigned short* Vtz = (unsigned short*)(wsb + 16*MB);
    unsigned short* xlt = (unsigned short*)(wsb + 22*MB);
    float* NB0    = (float*)(wsb + 23*MB);
    float* NB1    = (float*)(wsb + 34*MB);
    float* NB2    = (float*)(wsb + 45*MB);
    float* NB3    = (float*)(wsb + 56*MB);
    unsigned short* E = (unsigned short*)(wsb + 67*MB);   // [NN x KP] bf16 = 81.9 MB
    float* outp   = (float*)d_out;

    (void)hipMemsetAsync(deg, 0, NN*sizeof(int), stream);
    (void)hipMemsetAsync(cursor, 0, NN*sizeof(int), stream);
    (void)hipMemsetAsync(attn, 0, KK*128*sizeof(float), stream);
    (void)hipMemsetAsync(zbuf, 0, NN*sizeof(float), stream);

    // CSR build
    k_count<<<1250, 256, 0, stream>>>(edst, deg);
    k_dinv<<<79, 256, 0, stream>>>(deg, dinv);
    k_scan<<<1, 1024, 0, stream>>>(deg, rows);
    k_fill<<<1250, 256, 0, stream>>>(esrc, edst, rows, cursor, col);

    const int GN = 313;   // ceil(NN/64)
    const int GK = 32;    // ceil(KK/64) == KP/64

    // GCN1: h1 = relu(agg(x@W1 * dinv) * dinv + b1)
    gemm128<<<GN, 512, 0, stream>>>(x, W1, NB0, NN, dinv, nullptr, nullptr, 0);
    gcn_agg<<<5000, 256, 0, stream>>>(NB0, dinv, rows, col, b1, NB1, 1);
    // GCN2 -> h2 in NB2
    gemm128<<<GN, 512, 0, stream>>>(NB1, W2, NB0, NN, dinv, nullptr, nullptr, 0);
    gcn_agg<<<5000, 256, 0, stream>>>(NB0, dinv, rows, col, b2, NB2, 1);
    // Kd = gcn(h2, Wk, bk) -> NB1 -> Kbf
    gemm128<<<GN, 512, 0, stream>>>(NB2, Wk, NB0, NN, dinv, nullptr, nullptr, 0);
    gcn_agg<<<5000, 256, 0, stream>>>(NB0, dinv, rows, col, bk, NB1, 0);
    conv_bf16<<<2500, 256, 0, stream>>>(NB1, Kbf, NN*32);
    // Q = S@Wq + bq -> Qb -> Qbf
    gemm128<<<GK, 512, 0, stream>>>(S, Wq, Qb, KK, nullptr, bq, nullptr, 0);
    conv_bf16<<<250, 256, 0, stream>>>(Qb, Qbf, KK*32);
    // E = exp(SCALE * Kd Q^T), z row sums
    s_gemm_exp<<<dim3(GN, GK), 256, 0, stream>>>(Kbf, Qbf, E, zbuf);
    k_rcp<<<79, 256, 0, stream>>>(zbuf, zinv);
    // Vd = gcn(h2, Wv, bv) -> NB3 -> Vtz (transposed bf16, pre-scaled by zinv[n])
    gemm128<<<GN, 512, 0, stream>>>(NB2, Wv, NB0, NN, dinv, nullptr, nullptr, 0);
    gcn_agg<<<5000, 256, 0, stream>>>(NB0, dinv, rows, col, bv, NB3, 0);
    conv_bf16_T<<<dim3(GN, 2), 256, 0, stream>>>(NB3, Vtz, NN, NN, zinv);
    // attn[k][d] = sum_n E[n][k]*zinv[n]*V[n][d]
    attn_gemm<<<dim3(GK, ZSPLIT), 256, 0, stream>>>(E, Vtz, attn);
    // out = LN(Q + attn)
    ln_ker<<<KK, 128, 0, stream>>>(attn, Qb, g0, be0, o1);
    // o2 = o1 + relu(o1@Wo + bo)
    gemm128<<<GK, 512, 0, stream>>>(o1, Wo, o2, KK, nullptr, bo, o1, 1);
    ln_ker<<<KK, 128, 0, stream>>>(o2, nullptr, g1, be1, o3);
    // xl = o3@Wl + bl -> xlb -> xlt (transposed bf16, ld KP; pad cols read as 0 via E pad)
    gemm128<<<GK, 512, 0, stream>>>(o3, Wl, xlb, KK, nullptr, bl, nullptr, 0);
    conv_bf16_T<<<dim3(GK, 2), 256, 0, stream>>>(xlb, xlt, KK, KP, nullptr);
    // x_out[n][d] = zinv[n] * sum_k E[n][k]*xl[k][d]   (R=KP, E pad cols are zero)
    gemm_nt_scale<<<dim3(GN, 2), 256, 0, stream>>>(E, KP, NN, xlt, KP, 128, KP, NB0, 128, zinv);
    // GCN3
    gemm128<<<GN, 512, 0, stream>>>(NB0, W3, NB1, NN, dinv, nullptr, nullptr, 0);
    gcn_agg<<<5000, 256, 0, stream>>>(NB1, dinv, rows, col, b3, NB2, 1);
    // GCN4
    gemm128<<<GN, 512, 0, stream>>>(NB2, W4, NB0, NN, dinv, nullptr, nullptr, 0);
    gcn_agg<<<5000, 256, 0, stream>>>(NB0, dinv, rows, col, b4, NB1, 1);
    // GCN5 -> d_out
    gemm128<<<GN, 512, 0, stream>>>(NB1, W5, NB0, NN, dinv, nullptr, nullptr, 0);
    gcn_agg<<<5000, 256, 0, stream>>>(NB0, dinv, rows, col, b5, outp, 0);
}

// Round 6
// 690.433 us; speedup vs baseline: 1.6596x; 1.2946x over previous
//
#include <hip/hip_runtime.h>

#define NN 20000
#define EE 320000
#define KK 2000
#define KP 2048          // padded K-dim of E (zeros in 2000..2047)
#define SCALE 0.08838834764831845f
#define ZSPLIT 16        // attn_gemm partial slices
#define ACHUNKS 625      // 20000 / 32

typedef const float* cfp;
typedef __attribute__((ext_vector_type(8))) short sh8;
typedef __attribute__((ext_vector_type(4))) float f32x4;

static __device__ __forceinline__ float4 ld4(const float* p){ return *reinterpret_cast<const float4*>(p); }
static __device__ __forceinline__ void st4(float* p, float4 v){ *reinterpret_cast<float4*>(p) = v; }

static __device__ __forceinline__ unsigned short f2bf(float f){
    unsigned int u = __float_as_uint(f);
    u = (u + 0x7FFFu + ((u >> 16) & 1u)) >> 16;
    return (unsigned short)u;
}
static __device__ __forceinline__ float bf2f(unsigned short h){
    return __uint_as_float(((unsigned int)h) << 16);
}

// ---------------- CSR build ----------------
__global__ __launch_bounds__(256) void k_count(const int* dst, int* deg){
    int i = blockIdx.x*256 + threadIdx.x;
    if (i < EE) atomicAdd(&deg[dst[i]], 1);
}

__global__ __launch_bounds__(256) void k_dinv(const int* deg, float* dinv){
    int n = blockIdx.x*256 + threadIdx.x;
    if (n < NN) dinv[n] = rsqrtf((float)deg[n] + 1.0f);
}

__global__ __launch_bounds__(1024) void k_scan(const int* cnt, int* rows){
    __shared__ int part[1024];
    int t = threadIdx.x;
    int base = t*20;
    int s = 0;
    for (int i = 0; i < 20; ++i){ int idx = base+i; if (idx < NN) s += cnt[idx]; }
    part[t] = s; __syncthreads();
    for (int off = 1; off < 1024; off <<= 1){
        int v = (t >= off) ? part[t-off] : 0;
        __syncthreads();
        part[t] += v;
        __syncthreads();
    }
    int run = part[t] - s;   // exclusive
    for (int i = 0; i < 20; ++i){
        int idx = base+i;
        if (idx < NN){ rows[idx] = run; run += cnt[idx]; }
    }
    if (t == 0) rows[NN] = EE;
}

__global__ __launch_bounds__(256) void k_fill(const int* src, const int* dst, const int* rows,
                                              int* cursor, int* col){
    int i = blockIdx.x*256 + threadIdx.x;
    if (i < EE){
        int d = dst[i];
        int pos = rows[d] + atomicAdd(&cursor[d], 1);
        col[pos] = src[i];
    }
}

// ---------------- weight transpose+convert: 7x (W fp32 [128x128] -> Wt bf16 [128x128], Wt[o][i]=W[i][o]) ----------------
__global__ __launch_bounds__(256) void conv_wT(cfp w0, cfp w1, cfp w2, cfp w3, cfp w4, cfp w5, cfp w6,
                                               unsigned short* wts){
    const float* in;
    switch (blockIdx.z){
        case 0: in = w0; break; case 1: in = w1; break; case 2: in = w2; break;
        case 3: in = w3; break; case 4: in = w4; break; case 5: in = w5; break;
        default: in = w6; break;
    }
    unsigned short* out = wts + (size_t)blockIdx.z*16384;
    __shared__ float t[64][65];
    int r0 = blockIdx.x*64, c0 = blockIdx.y*64;
    int tid = threadIdx.x;
    for (int i = tid; i < 64*16; i += 256){
        int r = i >> 4, c4 = (i & 15) * 4;
        float4 v = ld4(in + (size_t)(r0+r)*128 + c0 + c4);
        t[r][c4+0]=v.x; t[r][c4+1]=v.y; t[r][c4+2]=v.z; t[r][c4+3]=v.w;
    }
    __syncthreads();
    for (int i = tid; i < 64*16; i += 256){
        int c = i >> 4, r4 = (i & 15) * 4;
        ushort4 o;
        o.x = f2bf(t[r4+0][c]); o.y = f2bf(t[r4+1][c]);
        o.z = f2bf(t[r4+2][c]); o.w = f2bf(t[r4+3][c]);
        *reinterpret_cast<ushort4*>(out + (size_t)(c0+c)*128 + r0 + r4) = o;
    }
}

// ---------------- fp32 GEMM  C[M x 128] = A[M x 128] @ W[128 x 128]  + epilogue (KK-sized only) ----------------
__global__ __launch_bounds__(512) void gemm128(const float* __restrict__ A, const float* __restrict__ Wm,
                                               float* __restrict__ C, int M,
                                               const float* bias, const float* resid, int relu){
    __shared__ __align__(16) float Ws[128*132];
    __shared__ float As[64*129];
    int tid = threadIdx.x;
    int r0 = blockIdx.x*64;
    for (int i = tid; i < 128*32; i += 512){
        int r = i >> 5, c4 = (i & 31) * 4;
        float4 v = ld4(Wm + r*128 + c4);
        st4(&Ws[r*132 + c4], v);
    }
    for (int i = tid; i < 64*32; i += 512){
        int r = i >> 5, c4 = (i & 31) * 4;
        float4 v = (r0 + r < M) ? ld4(A + (size_t)(r0+r)*128 + c4) : make_float4(0,0,0,0);
        As[r*129 + c4+0] = v.x; As[r*129 + c4+1] = v.y;
        As[r*129 + c4+2] = v.z; As[r*129 + c4+3] = v.w;
    }
    __syncthreads();
    int a = tid >> 5;
    int b = tid & 31;
    float acc[4][4] = {};
    #pragma unroll 4
    for (int d = 0; d < 128; ++d){
        float4 w = ld4(&Ws[d*132 + 4*b]);
        float wv[4] = {w.x, w.y, w.z, w.w};
        float av[4];
        #pragma unroll
        for (int i = 0; i < 4; ++i) av[i] = As[(4*a+i)*129 + d];
        #pragma unroll
        for (int i = 0; i < 4; ++i)
            #pragma unroll
            for (int j = 0; j < 4; ++j)
                acc[i][j] += av[i]*wv[j];
    }
    int cc = 4*b;
    #pragma unroll
    for (int i = 0; i < 4; ++i){
        int r = r0 + 4*a + i;
        if (r < M){
            float v[4];
            #pragma unroll
            for (int j = 0; j < 4; ++j) v[j] = acc[i][j];
            if (bias){
                #pragma unroll
                for (int j = 0; j < 4; ++j) v[j] += bias[cc+j];
            }
            if (relu){
                #pragma unroll
                for (int j = 0; j < 4; ++j) v[j] = fmaxf(v[j], 0.f);
            }
            if (resid){
                float4 rv = ld4(resid + (size_t)r*128 + cc);
                v[0]+=rv.x; v[1]+=rv.y; v[2]+=rv.z; v[3]+=rv.w;
            }
            st4(C + (size_t)r*128 + cc, make_float4(v[0],v[1],v[2],v[3]));
        }
    }
}

static __device__ __forceinline__ sh8 ldfrag(const unsigned short* base, int row, int lim, int ld, int off){
    if (row < lim) return *reinterpret_cast<const sh8*>(base + (size_t)row*ld + off);
    sh8 z = (sh8)0;
    return z;
}

// ---------------- bf16 MFMA GEMM: C[M x 128] = (A[M x 128] @ W) * rscale[row], bf16 out ----------------
// Wt is [128 x 128] bf16 with Wt[o][i] = W[i][o]
__global__ __launch_bounds__(256) void tgemm(const unsigned short* __restrict__ A, int M,
                                             const unsigned short* __restrict__ Wt,
                                             const float* __restrict__ rscale,
                                             unsigned short* __restrict__ C){
    int tid = threadIdx.x;
    int wave = tid >> 6, lane = tid & 63;
    int wm = wave >> 1, wn = wave & 1;
    int m_base = blockIdx.x*64 + wm*32;
    int n_base = blockIdx.y*64 + wn*32;
    int l15 = lane & 15;
    int roff = (lane >> 4) * 8;
    int rA0 = m_base + l15, rA1 = rA0 + 16;
    const unsigned short* b0p = Wt + (size_t)(n_base + l15)*128 + roff;
    const unsigned short* b1p = b0p + 16*128;
    f32x4 acc00 = (f32x4)0.f, acc01 = (f32x4)0.f, acc10 = (f32x4)0.f, acc11 = (f32x4)0.f;
    #pragma unroll
    for (int r = 0; r < 128; r += 32){
        sh8 a0 = ldfrag(A, rA0, M, 128, r + roff);
        sh8 a1 = ldfrag(A, rA1, M, 128, r + roff);
        sh8 b0 = *reinterpret_cast<const sh8*>(b0p + r);
        sh8 b1 = *reinterpret_cast<const sh8*>(b1p + r);
        acc00 = __builtin_amdgcn_mfma_f32_16x16x32_bf16(a0, b0, acc00, 0, 0, 0);
        acc01 = __builtin_amdgcn_mfma_f32_16x16x32_bf16(a0, b1, acc01, 0, 0, 0);
        acc10 = __builtin_amdgcn_mfma_f32_16x16x32_bf16(a1, b0, acc10, 0, 0, 0);
        acc11 = __builtin_amdgcn_mfma_f32_16x16x32_bf16(a1, b1, acc11, 0, 0, 0);
    }
    int rq = (lane >> 4) * 4;
    f32x4 accs[2][2] = {{acc00, acc01},{acc10, acc11}};
    #pragma unroll
    for (int mi = 0; mi < 2; ++mi){
        #pragma unroll
        for (int ni = 0; ni < 2; ++ni){
            f32x4 a = accs[mi][ni];
            int gn = n_base + ni*16 + l15;
            #pragma unroll
            for (int reg = 0; reg < 4; ++reg){
                int gm = m_base + mi*16 + rq + reg;
                if (gm < M) C[(size_t)gm*128 + gn] = f2bf(a[reg] * (rscale ? rscale[gm] : 1.f));
            }
        }
    }
}

// ---------------- GCN aggregation (bf16 in, fp32 accumulate, bf16 or fp32 out) ----------------
__global__ __launch_bounds__(256) void gcn_agg_bf(const unsigned short* __restrict__ y, const float* __restrict__ dinv,
                                                  const int* __restrict__ rows, const int* __restrict__ col,
                                                  const float* __restrict__ bias, void* __restrict__ outv,
                                                  int relu, int out_fp32){
    int wid = (int)((blockIdx.x*256 + threadIdx.x) >> 6);
    int lane = threadIdx.x & 63;
    if (wid >= NN) return;
    int f = lane*2;
    ushort2 u = *reinterpret_cast<const ushort2*>(y + (size_t)wid*128 + f);
    float ax = bf2f(u.x), ay = bf2f(u.y);
    int s = rows[wid], e = rows[wid+1];
    int j = s;
    int e2 = s + ((e - s) & ~1);
    for (; j < e2; j += 2){
        int c0 = col[j], c1 = col[j+1];
        ushort2 v0 = *reinterpret_cast<const ushort2*>(y + (size_t)c0*128 + f);
        ushort2 v1 = *reinterpret_cast<const ushort2*>(y + (size_t)c1*128 + f);
        ax += bf2f(v0.x) + bf2f(v1.x);
        ay += bf2f(v0.y) + bf2f(v1.y);
    }
    if (j < e){
        int c0 = col[j];
        ushort2 v0 = *reinterpret_cast<const ushort2*>(y + (size_t)c0*128 + f);
        ax += bf2f(v0.x); ay += bf2f(v0.y);
    }
    float dn = dinv[wid];
    float ox = ax*dn + bias[f];
    float oy = ay*dn + bias[f+1];
    if (relu){ ox = fmaxf(ox, 0.f); oy = fmaxf(oy, 0.f); }
    if (out_fp32){
        *reinterpret_cast<float2*>((float*)outv + (size_t)wid*128 + f) = make_float2(ox, oy);
    } else {
        ushort2 o; o.x = f2bf(ox); o.y = f2bf(oy);
        *reinterpret_cast<ushort2*>((unsigned short*)outv + (size_t)wid*128 + f) = o;
    }
}

// ---------------- convert fp32 -> bf16 (same layout) ----------------
__global__ __launch_bounds__(256) void conv_bf16(const float* __restrict__ in, unsigned short* __restrict__ out, int n4){
    int i = blockIdx.x*256 + threadIdx.x;
    if (i < n4){
        float4 v = ld4(in + (size_t)i*4);
        ushort4 o;
        o.x = f2bf(v.x); o.y = f2bf(v.y); o.z = f2bf(v.z); o.w = f2bf(v.w);
        *reinterpret_cast<ushort4*>(out + (size_t)i*4) = o;
    }
}

// ---------------- convert + transpose (+ optional per-source-row scale): fp32 [M x 128] -> bf16 [128 x ldout] ----------------
__global__ __launch_bounds__(256) void conv_bf16_T(const float* __restrict__ in, unsigned short* __restrict__ out,
                                                   int M, int ldout, const float* __restrict__ rscale){
    __shared__ float t[64][65];
    int r0 = blockIdx.x*64, c0 = blockIdx.y*64;
    int tid = threadIdx.x;
    for (int i = tid; i < 64*16; i += 256){
        int r = i >> 4, c4 = (i & 15) * 4;
        float4 v = (r0 + r < M) ? ld4(in + (size_t)(r0+r)*128 + c0 + c4) : make_float4(0,0,0,0);
        if (rscale && r0 + r < M){
            float sc = rscale[r0 + r];
            v.x *= sc; v.y *= sc; v.z *= sc; v.w *= sc;
        }
        t[r][c4+0]=v.x; t[r][c4+1]=v.y; t[r][c4+2]=v.z; t[r][c4+3]=v.w;
    }
    __syncthreads();
    for (int i = tid; i < 64*16; i += 256){
        int c = i >> 4, r4 = (i & 15) * 4;
        if (r0 + r4 < M){
            ushort4 o;
            o.x = f2bf(t[r4+0][c]); o.y = f2bf(t[r4+1][c]);
            o.z = f2bf(t[r4+2][c]); o.w = f2bf(t[r4+3][c]);
            *reinterpret_cast<ushort4*>(out + (size_t)(c0+c)*ldout + r0 + r4) = o;
        }
    }
}

__global__ __launch_bounds__(256) void k_rcp32(const float* __restrict__ zp, float* __restrict__ zinv){
    int n = blockIdx.x*256 + threadIdx.x;
    if (n < NN){
        float s = 0.f;
        #pragma unroll
        for (int y = 0; y < 32; ++y) s += zp[(size_t)y*NN + n];
        zinv[n] = 1.f / s;
    }
}

// ---------------- S-GEMM + exp + z-partials: E[n][k] = exp(SCALE * Kd[n].Q[k]) ----------------
__global__ __launch_bounds__(256) void s_gemm_exp(const unsigned short* __restrict__ Kb,
                                                  const unsigned short* __restrict__ Qb2,
                                                  unsigned short* __restrict__ E, float* __restrict__ zpart){
    __shared__ unsigned short Es[64*68];
    int tid = threadIdx.x;
    int wave = tid >> 6, lane = tid & 63;
    int wm = wave >> 1, wn = wave & 1;
    int n_blk = blockIdx.x*64, k_blk = blockIdx.y*64;
    int m_base = n_blk + wm*32;
    int k_base = k_blk + wn*32;
    int l15 = lane & 15;
    int roff = (lane >> 4) * 8;
    int rA0 = m_base + l15, rA1 = rA0 + 16;
    int rB0 = k_base + l15, rB1 = rB0 + 16;
    f32x4 acc00 = (f32x4)0.f, acc01 = (f32x4)0.f, acc10 = (f32x4)0.f, acc11 = (f32x4)0.f;
    #pragma unroll
    for (int r = 0; r < 128; r += 32){
        sh8 a0 = ldfrag(Kb, rA0, NN, 128, r + roff);
        sh8 a1 = ldfrag(Kb, rA1, NN, 128, r + roff);
        sh8 b0 = ldfrag(Qb2, rB0, KK, 128, r + roff);
        sh8 b1 = ldfrag(Qb2, rB1, KK, 128, r + roff);
        acc00 = __builtin_amdgcn_mfma_f32_16x16x32_bf16(a0, b0, acc00, 0, 0, 0);
        acc01 = __builtin_amdgcn_mfma_f32_16x16x32_bf16(a0, b1, acc01, 0, 0, 0);
        acc10 = __builtin_amdgcn_mfma_f32_16x16x32_bf16(a1, b0, acc10, 0, 0, 0);
        acc11 = __builtin_amdgcn_mfma_f32_16x16x32_bf16(a1, b1, acc11, 0, 0, 0);
    }
    int rq = (lane >> 4) * 4;
    f32x4 accs[2][2] = {{acc00, acc01},{acc10, acc11}};
    #pragma unroll
    for (int mi = 0; mi < 2; ++mi){
        #pragma unroll
        for (int ni = 0; ni < 2; ++ni){
            f32x4 a = accs[mi][ni];
            int c_loc = wn*32 + ni*16 + l15;
            bool kv = (k_blk + c_loc) < KK;
            #pragma unroll
            for (int reg = 0; reg < 4; ++reg){
                int r_loc = wm*32 + mi*16 + rq + reg;
                float e = kv ? __expf(a[reg]*SCALE) : 0.f;
                Es[r_loc*68 + c_loc] = f2bf(e);
            }
        }
    }
    __syncthreads();
    // per-row partial z for this k-slice (unique (y, n) -> no atomics)
    if (tid < 64){
        int n = n_blk + tid;
        if (n < NN){
            float s = 0.f;
            #pragma unroll 8
            for (int j = 0; j < 64; ++j) s += bf2f(Es[tid*68 + j]);
            zpart[(size_t)blockIdx.y*NN + n] = s;
        }
    }
    // coalesced store (16B chunks)
    for (int i = tid; i < 512; i += 256){
        int r = i >> 3, c8 = (i & 7) * 8;
        if (n_blk + r < NN){
            ushort4 lo = *reinterpret_cast<const ushort4*>(&Es[r*68 + c8]);
            ushort4 hi = *reinterpret_cast<const ushort4*>(&Es[r*68 + c8 + 4]);
            unsigned short* dst = E + (size_t)(n_blk + r)*KP + k_blk + c8;
            *reinterpret_cast<ushort4*>(dst) = lo;
            *reinterpret_cast<ushort4*>(dst + 4) = hi;
        }
    }
}

// ---------------- attn GEMM partials: part[y][kk][d] = sum_{n in slice} E[n][kk] * Vtz[d][n] ----------------
__global__ __launch_bounds__(256) void attn_gemm(const unsigned short* __restrict__ E,
                                                 const unsigned short* __restrict__ Vt,
                                                 float* __restrict__ part){
    __shared__ unsigned short As[64*36];
    int tid = threadIdx.x;
    int wave = tid >> 6, lane = tid & 63;
    int kk0 = blockIdx.x*64;
    int per = (ACHUNKS + ZSPLIT - 1) / ZSPLIT;
    int c0 = blockIdx.y*per;
    int c1 = min(ACHUNKS, c0 + per);
    int l15 = lane & 15;
    int q8 = (lane >> 4) * 8;
    int d0 = wave*32;
    int n_l = tid & 31;
    int k8 = (tid >> 5) * 8;
    f32x4 acc[4][2];
    #pragma unroll
    for (int g = 0; g < 4; ++g){ acc[g][0] = (f32x4)0.f; acc[g][1] = (f32x4)0.f; }
    for (int ch = c0; ch < c1; ++ch){
        int r0 = ch*32;
        {
            const unsigned short* prow = E + (size_t)(r0 + n_l)*KP + kk0 + k8;
            unsigned short tmp[8];
            *reinterpret_cast<sh8*>(tmp) = *reinterpret_cast<const sh8*>(prow);
            #pragma unroll
            for (int j = 0; j < 8; ++j) As[(k8 + j)*36 + n_l] = tmp[j];
        }
        __syncthreads();
        const unsigned short* vb = Vt + (size_t)(d0 + l15)*NN + r0 + q8;
        sh8 b0 = *reinterpret_cast<const sh8*>(vb);
        sh8 b1 = *reinterpret_cast<const sh8*>(vb + (size_t)16*NN);
        #pragma unroll
        for (int g = 0; g < 4; ++g){
            const unsigned short* ap = &As[(g*16 + l15)*36 + q8];
            union { struct { ushort4 lo, hi; } u; sh8 v; } af;
            af.u.lo = *reinterpret_cast<const ushort4*>(ap);
            af.u.hi = *reinterpret_cast<const ushort4*>(ap + 4);
            acc[g][0] = __builtin_amdgcn_mfma_f32_16x16x32_bf16(af.v, b0, acc[g][0], 0, 0, 0);
            acc[g][1] = __builtin_amdgcn_mfma_f32_16x16x32_bf16(af.v, b1, acc[g][1], 0, 0, 0);
        }
        __syncthreads();
    }
    float* pbase = part + (size_t)blockIdx.y*KK*128;
    int rq = (lane >> 4) * 4;
    #pragma unroll
    for (int g = 0; g < 4; ++g){
        #pragma unroll
        for (int ni = 0; ni < 2; ++ni){
            int d = d0 + ni*16 + l15;
            #pragma unroll
            for (int reg = 0; reg < 4; ++reg){
                int kk = kk0 + g*16 + rq + reg;
                if (kk < KK) pbase[(size_t)kk*128 + d] = acc[g][ni][reg];
            }
        }
    }
}

// ---------------- xout GEMM: xr[n][d] = bf16( zinv[n] * sum_k E[n][k] * xlt[d][k] ), k-unroll 64 ----------------
__global__ __launch_bounds__(256) void xout_gemm(const unsigned short* __restrict__ E,
                                                 const unsigned short* __restrict__ B,
                                                 const float* __restrict__ zinv,
                                                 unsigned short* __restrict__ xr){
    int tid = threadIdx.x;
    int wave = tid >> 6, lane = tid & 63;
    int wm = wave >> 1, wn = wave & 1;
    int m_base = blockIdx.x*64 + wm*32;
    int n_base = blockIdx.y*64 + wn*32;
    int l15 = lane & 15;
    int roff = (lane >> 4) * 8;
    int rA0 = m_base + l15, rA1 = rA0 + 16;
    const unsigned short* bp0 = B + (size_t)(n_base + l15)*KP + roff;
    const unsigned short* bp1 = bp0 + (size_t)16*KP;
    f32x4 acc00 = (f32x4)0.f, acc01 = (f32x4)0.f, acc10 = (f32x4)0.f, acc11 = (f32x4)0.f;
    for (int r = 0; r < KP; r += 64){
        sh8 a0 = ldfrag(E, rA0, NN, KP, r + roff);
        sh8 a1 = ldfrag(E, rA1, NN, KP, r + roff);
        sh8 b0 = *reinterpret_cast<const sh8*>(bp0 + r);
        sh8 b1 = *reinterpret_cast<const sh8*>(bp1 + r);
        sh8 a2 = ldfrag(E, rA0, NN, KP, r + 32 + roff);
        sh8 a3 = ldfrag(E, rA1, NN, KP, r + 32 + roff);
        sh8 b2 = *reinterpret_cast<const sh8*>(bp0 + r + 32);
        sh8 b3 = *reinterpret_cast<const sh8*>(bp1 + r + 32);
        acc00 = __builtin_amdgcn_mfma_f32_16x16x32_bf16(a0, b0, acc00, 0, 0, 0);
        acc01 = __builtin_amdgcn_mfma_f32_16x16x32_bf16(a0, b1, acc01, 0, 0, 0);
        acc10 = __builtin_amdgcn_mfma_f32_16x16x32_bf16(a1, b0, acc10, 0, 0, 0);
        acc11 = __builtin_amdgcn_mfma_f32_16x16x32_bf16(a1, b1, acc11, 0, 0, 0);
        acc00 = __builtin_amdgcn_mfma_f32_16x16x32_bf16(a2, b2, acc00, 0, 0, 0);
        acc01 = __builtin_amdgcn_mfma_f32_16x16x32_bf16(a2, b3, acc01, 0, 0, 0);
        acc10 = __builtin_amdgcn_mfma_f32_16x16x32_bf16(a3, b2, acc10, 0, 0, 0);
        acc11 = __builtin_amdgcn_mfma_f32_16x16x32_bf16(a3, b3, acc11, 0, 0, 0);
    }
    int rq = (lane >> 4) * 4;
    f32x4 accs[2][2] = {{acc00, acc01},{acc10, acc11}};
    #pragma unroll
    for (int mi = 0; mi < 2; ++mi){
        #pragma unroll
        for (int ni = 0; ni < 2; ++ni){
            f32x4 a = accs[mi][ni];
            int gn = n_base + ni*16 + l15;
            #pragma unroll
            for (int reg = 0; reg < 4; ++reg){
                int gm = m_base + mi*16 + rq + reg;
                if (gm < NN) xr[(size_t)gm*128 + gn] = f2bf(a[reg]*zinv[gm]);
            }
        }
    }
}

// ---------------- LayerNorm over D=128 (with partial-sum input) ----------------
__global__ __launch_bounds__(128) void ln_ker(const float* __restrict__ in, int nparts,
                                              const float* __restrict__ resid,
                                              const float* __restrict__ g, const float* __restrict__ be,
                                              float* __restrict__ out){
    __shared__ float rs[128], rq[128];
    int r = blockIdx.x, t = threadIdx.x;
    float v = 0.f;
    for (int p = 0; p < nparts; ++p) v += in[(size_t)p*KK*128 + r*128 + t];
    if (resid) v += resid[r*128 + t];
    rs[t] = v; rq[t] = v*v;
    __syncthreads();
    for (int off = 64; off > 0; off >>= 1){
        if (t < off){ rs[t] += rs[t+off]; rq[t] += rq[t+off]; }
        __syncthreads();
    }
    float mean = rs[0]*(1.f/128.f);
    float var = rq[0]*(1.f/128.f) - mean*mean;
    out[r*128 + t] = (v - mean)*rsqrtf(var + 1e-5f)*g[t] + be[t];
}

// ---------------- launcher ----------------
extern "C" void kernel_launch(void* const* d_in, const int* in_sizes, int n_in,
                              void* d_out, int out_size, void* d_ws, size_t ws_size,
                              hipStream_t stream){
    cfp x  = (cfp)d_in[0];
    const int* ei = (const int*)d_in[1];
    const int* esrc = ei;
    const int* edst = ei + EE;
    cfp W1=(cfp)d_in[3], b1=(cfp)d_in[4], W2=(cfp)d_in[5], b2=(cfp)d_in[6];
    cfp S =(cfp)d_in[7];
    cfp Wq=(cfp)d_in[8],  bq=(cfp)d_in[9],  Wk=(cfp)d_in[10], bk=(cfp)d_in[11];
    cfp Wv=(cfp)d_in[12], bv=(cfp)d_in[13], Wo=(cfp)d_in[14], bo=(cfp)d_in[15];
    cfp g0=(cfp)d_in[16], be0=(cfp)d_in[17], g1=(cfp)d_in[18], be1=(cfp)d_in[19];
    cfp Wl=(cfp)d_in[20], bl=(cfp)d_in[21], W3=(cfp)d_in[22], b3=(cfp)d_in[23];
    cfp W4=(cfp)d_in[24], b4=(cfp)d_in[25], W5=(cfp)d_in[26], b5=(cfp)d_in[27];

    char* wsb = (char*)d_ws;
    const size_t MB = 1048576;
    int*   deg    = (int*)  (wsb + 0);
    float* dinv   = (float*)(wsb + 81920);
    int*   rows   = (int*)  (wsb + 163840);
    int*   cursor = (int*)  (wsb + 245760);
    int*   col    = (int*)  (wsb + 327680);
    float* Qb     = (float*)(wsb + 2*MB);
    float* o1     = (float*)(wsb + 3*MB);
    float* o2     = (float*)(wsb + 4*MB);
    float* o3     = (float*)(wsb + 5*MB);
    float* xlb    = (float*)(wsb + 6*MB);
    float* zpart  = (float*)(wsb + 7*MB);                 // 32 x NN fp32 = 2.56 MB
    float* zinv   = (float*)(wsb + 10*MB);
    unsigned short* Wts = (unsigned short*)(wsb + 10*MB + 131072);  // 7 x 128x128 bf16
    unsigned short* Qbf = (unsigned short*)(wsb + 11*MB);
    unsigned short* xlt = (unsigned short*)(wsb + 11*MB + 524288);  // [128 x KP] bf16
    unsigned short* xbf = (unsigned short*)(wsb + 12*MB); // also h3
    unsigned short* h1  = (unsigned short*)(wsb + 17*MB); // also h4
    unsigned short* h2  = (unsigned short*)(wsb + 22*MB);
    unsigned short* ybuf= (unsigned short*)(wsb + 27*MB);
    unsigned short* Kbf = (unsigned short*)(wsb + 32*MB); // also xr
    unsigned short* Vtz = (unsigned short*)(wsb + 37*MB);
    float* NB3    = (float*)(wsb + 42*MB);                // 10.24 MB fp32
    float* part   = (float*)(wsb + 52*MB);                // ZSPLIT x KK x 128 fp32 = 16.4 MB
    unsigned short* E = (unsigned short*)(wsb + 68*MB);   // [NN x KP] bf16 = 78.1 MiB
    float* outp   = (float*)d_out;
    unsigned short* h3 = xbf;
    unsigned short* h4 = h1;
    unsigned short* xr = Kbf;

    (void)hipMemsetAsync(deg, 0, NN*sizeof(int), stream);
    (void)hipMemsetAsync(cursor, 0, NN*sizeof(int), stream);

    // CSR build
    k_count<<<1250, 256, 0, stream>>>(edst, deg);
    k_dinv<<<79, 256, 0, stream>>>(deg, dinv);
    k_scan<<<1, 1024, 0, stream>>>(deg, rows);
    k_fill<<<1250, 256, 0, stream>>>(esrc, edst, rows, cursor, col);

    // weights -> bf16 transposed; x -> bf16
    conv_wT<<<dim3(2,2,7), 256, 0, stream>>>(W1, W2, Wk, Wv, W3, W4, W5, Wts);
    conv_bf16<<<2500, 256, 0, stream>>>(x, xbf, NN*32);
    unsigned short* W1t = Wts;
    unsigned short* W2t = Wts + 16384;
    unsigned short* Wkt = Wts + 2*16384;
    unsigned short* Wvt = Wts + 3*16384;
    unsigned short* W3t = Wts + 4*16384;
    unsigned short* W4t = Wts + 5*16384;
    unsigned short* W5t = Wts + 6*16384;

    const int GN = 313;   // ceil(NN/64)
    const int GK = 32;    // ceil(KK/64) == KP/64

    // GCN1
    tgemm<<<dim3(GN,2), 256, 0, stream>>>(xbf, NN, W1t, dinv, ybuf);
    gcn_agg_bf<<<5000, 256, 0, stream>>>(ybuf, dinv, rows, col, b1, h1, 1, 0);
    // GCN2 -> h2
    tgemm<<<dim3(GN,2), 256, 0, stream>>>(h1, NN, W2t, dinv, ybuf);
    gcn_agg_bf<<<5000, 256, 0, stream>>>(ybuf, dinv, rows, col, b2, h2, 1, 0);
    // Kd -> Kbf (bf16)
    tgemm<<<dim3(GN,2), 256, 0, stream>>>(h2, NN, Wkt, dinv, ybuf);
    gcn_agg_bf<<<5000, 256, 0, stream>>>(ybuf, dinv, rows, col, bk, Kbf, 0, 0);
    // Q = S@Wq + bq (fp32) -> Qbf
    gemm128<<<GK, 512, 0, stream>>>(S, Wq, Qb, KK, bq, nullptr, 0);
    conv_bf16<<<250, 256, 0, stream>>>(Qb, Qbf, KK*32);
    // E = exp(SCALE * Kd Q^T), z partials
    s_gemm_exp<<<dim3(GN, GK), 256, 0, stream>>>(Kbf, Qbf, E, zpart);
    k_rcp32<<<79, 256, 0, stream>>>(zpart, zinv);
    // Vd -> NB3 (fp32) -> Vtz (transposed bf16, pre-scaled by zinv[n])
    tgemm<<<dim3(GN,2), 256, 0, stream>>>(h2, NN, Wvt, dinv, ybuf);
    gcn_agg_bf<<<5000, 256, 0, stream>>>(ybuf, dinv, rows, col, bv, NB3, 0, 1);
    conv_bf16_T<<<dim3(GN, 2), 256, 0, stream>>>(NB3, Vtz, NN, NN, zinv);
    // attn partials
    attn_gemm<<<dim3(GK, ZSPLIT), 256, 0, stream>>>(E, Vtz, part);
    // out = LN(sum(part) + Q)
    ln_ker<<<KK, 128, 0, stream>>>(part, ZSPLIT, Qb, g0, be0, o1);
    // o2 = o1 + relu(o1@Wo + bo)
    gemm128<<<GK, 512, 0, stream>>>(o1, Wo, o2, KK, bo, o1, 1);
    ln_ker<<<KK, 128, 0, stream>>>(o2, 1, nullptr, g1, be1, o3);
    // xl = o3@Wl + bl -> xlt (transposed bf16, ld KP)
    gemm128<<<GK, 512, 0, stream>>>(o3, Wl, xlb, KK, bl, nullptr, 0);
    conv_bf16_T<<<dim3(GK, 2), 256, 0, stream>>>(xlb, xlt, KK, KP, nullptr);
    // xr[n] = bf16(zinv[n] * E[n] @ xl)
    xout_gemm<<<dim3(GN, 2), 256, 0, stream>>>(E, xlt, zinv, xr);
    // GCN3
    tgemm<<<dim3(GN,2), 256, 0, stream>>>(xr, NN, W3t, dinv, ybuf);
    gcn_agg_bf<<<5000, 256, 0, stream>>>(ybuf, dinv, rows, col, b3, h3, 1, 0);
    // GCN4
    tgemm<<<dim3(GN,2), 256, 0, stream>>>(h3, NN, W4t, dinv, ybuf);
    gcn_agg_bf<<<5000, 256, 0, stream>>>(ybuf, dinv, rows, col, b4, h4, 1, 0);
    // GCN5 -> d_out (fp32)
    tgemm<<<dim3(GN,2), 256, 0, stream>>>(h4, NN, W5t, dinv, ybuf);
    gcn_agg_bf<<<5000, 256, 0, stream>>>(ybuf, dinv, rows, col, b5, outp, 0, 1);
}

// Round 7
// 638.154 us; speedup vs baseline: 1.7956x; 1.0819x over previous
//
#include <hip/hip_runtime.h>

#define NN 20000
#define EE 320000
#define KK 2000
#define KP 2048          // padded K-dim of E (zeros in 2000..2047)
#define SCALE 0.08838834764831845f
#define ZSPLIT 16        // attn_gemm partial slices
#define ACHUNKS 625      // 20000 / 32

typedef const float* cfp;
typedef __attribute__((ext_vector_type(8))) short sh8;
typedef __attribute__((ext_vector_type(4))) float f32x4;

static __device__ __forceinline__ float4 ld4(const float* p){ return *reinterpret_cast<const float4*>(p); }
static __device__ __forceinline__ void st4(float* p, float4 v){ *reinterpret_cast<float4*>(p) = v; }

static __device__ __forceinline__ unsigned short f2bf(float f){
    unsigned int u = __float_as_uint(f);
    u = (u + 0x7FFFu + ((u >> 16) & 1u)) >> 16;
    return (unsigned short)u;
}
static __device__ __forceinline__ float bf2f(unsigned short h){
    return __uint_as_float(((unsigned int)h) << 16);
}
static __device__ __forceinline__ sh8 lds8(const unsigned short* p){ return *reinterpret_cast<const sh8*>(p); }

// ---------------- CSR build ----------------
__global__ __launch_bounds__(256) void k_count(const int* dst, int* deg){
    int i = blockIdx.x*256 + threadIdx.x;
    if (i < EE) atomicAdd(&deg[dst[i]], 1);
}

__global__ __launch_bounds__(256) void k_dinv(const int* deg, float* dinv){
    int n = blockIdx.x*256 + threadIdx.x;
    if (n < NN) dinv[n] = rsqrtf((float)deg[n] + 1.0f);
}

__global__ __launch_bounds__(1024) void k_scan(const int* cnt, int* rows){
    __shared__ int part[1024];
    int t = threadIdx.x;
    int base = t*20;
    int s = 0;
    for (int i = 0; i < 20; ++i){ int idx = base+i; if (idx < NN) s += cnt[idx]; }
    part[t] = s; __syncthreads();
    for (int off = 1; off < 1024; off <<= 1){
        int v = (t >= off) ? part[t-off] : 0;
        __syncthreads();
        part[t] += v;
        __syncthreads();
    }
    int run = part[t] - s;   // exclusive
    for (int i = 0; i < 20; ++i){
        int idx = base+i;
        if (idx < NN){ rows[idx] = run; run += cnt[idx]; }
    }
    if (t == 0) rows[NN] = EE;
}

__global__ __launch_bounds__(256) void k_fill(const int* src, const int* dst, const int* rows,
                                              int* cursor, int* col){
    int i = blockIdx.x*256 + threadIdx.x;
    if (i < EE){
        int d = dst[i];
        int pos = rows[d] + atomicAdd(&cursor[d], 1);
        col[pos] = src[i];
    }
}

// ---------------- weight transpose+convert ----------------
__global__ __launch_bounds__(256) void conv_wT(cfp w0, cfp w1, cfp w2, cfp w3, cfp w4, cfp w5, cfp w6,
                                               unsigned short* wts){
    const float* in;
    switch (blockIdx.z){
        case 0: in = w0; break; case 1: in = w1; break; case 2: in = w2; break;
        case 3: in = w3; break; case 4: in = w4; break; case 5: in = w5; break;
        default: in = w6; break;
    }
    unsigned short* out = wts + (size_t)blockIdx.z*16384;
    __shared__ float t[64][65];
    int r0 = blockIdx.x*64, c0 = blockIdx.y*64;
    int tid = threadIdx.x;
    for (int i = tid; i < 64*16; i += 256){
        int r = i >> 4, c4 = (i & 15) * 4;
        float4 v = ld4(in + (size_t)(r0+r)*128 + c0 + c4);
        t[r][c4+0]=v.x; t[r][c4+1]=v.y; t[r][c4+2]=v.z; t[r][c4+3]=v.w;
    }
    __syncthreads();
    for (int i = tid; i < 64*16; i += 256){
        int c = i >> 4, r4 = (i & 15) * 4;
        ushort4 o;
        o.x = f2bf(t[r4+0][c]); o.y = f2bf(t[r4+1][c]);
        o.z = f2bf(t[r4+2][c]); o.w = f2bf(t[r4+3][c]);
        *reinterpret_cast<ushort4*>(out + (size_t)(c0+c)*128 + r0 + r4) = o;
    }
}

// ---------------- fp32 GEMM (KK-sized only) ----------------
__global__ __launch_bounds__(512) void gemm128(const float* __restrict__ A, const float* __restrict__ Wm,
                                               float* __restrict__ C, int M,
                                               const float* bias, const float* resid, int relu){
    __shared__ __align__(16) float Ws[128*132];
    __shared__ float As[64*129];
    int tid = threadIdx.x;
    int r0 = blockIdx.x*64;
    for (int i = tid; i < 128*32; i += 512){
        int r = i >> 5, c4 = (i & 31) * 4;
        float4 v = ld4(Wm + r*128 + c4);
        st4(&Ws[r*132 + c4], v);
    }
    for (int i = tid; i < 64*32; i += 512){
        int r = i >> 5, c4 = (i & 31) * 4;
        float4 v = (r0 + r < M) ? ld4(A + (size_t)(r0+r)*128 + c4) : make_float4(0,0,0,0);
        As[r*129 + c4+0] = v.x; As[r*129 + c4+1] = v.y;
        As[r*129 + c4+2] = v.z; As[r*129 + c4+3] = v.w;
    }
    __syncthreads();
    int a = tid >> 5;
    int b = tid & 31;
    float acc[4][4] = {};
    #pragma unroll 4
    for (int d = 0; d < 128; ++d){
        float4 w = ld4(&Ws[d*132 + 4*b]);
        float wv[4] = {w.x, w.y, w.z, w.w};
        float av[4];
        #pragma unroll
        for (int i = 0; i < 4; ++i) av[i] = As[(4*a+i)*129 + d];
        #pragma unroll
        for (int i = 0; i < 4; ++i)
            #pragma unroll
            for (int j = 0; j < 4; ++j)
                acc[i][j] += av[i]*wv[j];
    }
    int cc = 4*b;
    #pragma unroll
    for (int i = 0; i < 4; ++i){
        int r = r0 + 4*a + i;
        if (r < M){
            float v[4];
            #pragma unroll
            for (int j = 0; j < 4; ++j) v[j] = acc[i][j];
            if (bias){
                #pragma unroll
                for (int j = 0; j < 4; ++j) v[j] += bias[cc+j];
            }
            if (relu){
                #pragma unroll
                for (int j = 0; j < 4; ++j) v[j] = fmaxf(v[j], 0.f);
            }
            if (resid){
                float4 rv = ld4(resid + (size_t)r*128 + cc);
                v[0]+=rv.x; v[1]+=rv.y; v[2]+=rv.z; v[3]+=rv.w;
            }
            st4(C + (size_t)r*128 + cc, make_float4(v[0],v[1],v[2],v[3]));
        }
    }
}

// ---------------- bf16 MFMA GEMM: C[M x 128] = (A@W)*rscale, bf16 out. Unchecked A reads (ws slack). ----------------
__global__ __launch_bounds__(256) void tgemm(const unsigned short* __restrict__ A, int M,
                                             const unsigned short* __restrict__ Wt,
                                             const float* __restrict__ rscale,
                                             unsigned short* __restrict__ C){
    int tid = threadIdx.x;
    int wave = tid >> 6, lane = tid & 63;
    int wm = wave >> 1, wn = wave & 1;
    int m_base = blockIdx.x*64 + wm*32;
    int n_base = blockIdx.y*64 + wn*32;
    int l15 = lane & 15;
    int roff = (lane >> 4) * 8;
    const unsigned short* ap0 = A + (size_t)(m_base + l15)*128 + roff;
    const unsigned short* ap1 = ap0 + 16*128;
    const unsigned short* b0p = Wt + (size_t)(n_base + l15)*128 + roff;
    const unsigned short* b1p = b0p + 16*128;
    f32x4 acc00 = (f32x4)0.f, acc01 = (f32x4)0.f, acc10 = (f32x4)0.f, acc11 = (f32x4)0.f;
    #pragma unroll
    for (int r = 0; r < 128; r += 32){
        sh8 a0 = lds8(ap0 + r);
        sh8 a1 = lds8(ap1 + r);
        sh8 b0 = lds8(b0p + r);
        sh8 b1 = lds8(b1p + r);
        acc00 = __builtin_amdgcn_mfma_f32_16x16x32_bf16(a0, b0, acc00, 0, 0, 0);
        acc01 = __builtin_amdgcn_mfma_f32_16x16x32_bf16(a0, b1, acc01, 0, 0, 0);
        acc10 = __builtin_amdgcn_mfma_f32_16x16x32_bf16(a1, b0, acc10, 0, 0, 0);
        acc11 = __builtin_amdgcn_mfma_f32_16x16x32_bf16(a1, b1, acc11, 0, 0, 0);
    }
    int rq = (lane >> 4) * 4;
    f32x4 accs[2][2] = {{acc00, acc01},{acc10, acc11}};
    #pragma unroll
    for (int mi = 0; mi < 2; ++mi){
        #pragma unroll
        for (int ni = 0; ni < 2; ++ni){
            f32x4 a = accs[mi][ni];
            int gn = n_base + ni*16 + l15;
            #pragma unroll
            for (int reg = 0; reg < 4; ++reg){
                int gm = m_base + mi*16 + rq + reg;
                if (gm < M) C[(size_t)gm*128 + gn] = f2bf(a[reg] * (rscale ? rscale[gm] : 1.f));
            }
        }
    }
}

// ---------------- GCN aggregation (bf16 in, fp32 accumulate), neighbor unroll 4 ----------------
__global__ __launch_bounds__(256) void gcn_agg_bf(const unsigned short* __restrict__ y, const float* __restrict__ dinv,
                                                  const int* __restrict__ rows, const int* __restrict__ col,
                                                  const float* __restrict__ bias, void* __restrict__ outv,
                                                  int relu, int out_fp32){
    int wid = (int)((blockIdx.x*256 + threadIdx.x) >> 6);
    int lane = threadIdx.x & 63;
    if (wid >= NN) return;
    int f = lane*2;
    ushort2 u = *reinterpret_cast<const ushort2*>(y + (size_t)wid*128 + f);
    float ax = bf2f(u.x), ay = bf2f(u.y);
    int s = rows[wid], e = rows[wid+1];
    int j = s;
    int e4 = s + ((e - s) & ~3);
    for (; j < e4; j += 4){
        int c0 = col[j], c1 = col[j+1], c2 = col[j+2], c3 = col[j+3];
        ushort2 v0 = *reinterpret_cast<const ushort2*>(y + (size_t)c0*128 + f);
        ushort2 v1 = *reinterpret_cast<const ushort2*>(y + (size_t)c1*128 + f);
        ushort2 v2 = *reinterpret_cast<const ushort2*>(y + (size_t)c2*128 + f);
        ushort2 v3 = *reinterpret_cast<const ushort2*>(y + (size_t)c3*128 + f);
        ax += bf2f(v0.x) + bf2f(v1.x) + bf2f(v2.x) + bf2f(v3.x);
        ay += bf2f(v0.y) + bf2f(v1.y) + bf2f(v2.y) + bf2f(v3.y);
    }
    for (; j < e; ++j){
        int c0 = col[j];
        ushort2 v0 = *reinterpret_cast<const ushort2*>(y + (size_t)c0*128 + f);
        ax += bf2f(v0.x); ay += bf2f(v0.y);
    }
    float dn = dinv[wid];
    float ox = ax*dn + bias[f];
    float oy = ay*dn + bias[f+1];
    if (relu){ ox = fmaxf(ox, 0.f); oy = fmaxf(oy, 0.f); }
    if (out_fp32){
        *reinterpret_cast<float2*>((float*)outv + (size_t)wid*128 + f) = make_float2(ox, oy);
    } else {
        ushort2 o; o.x = f2bf(ox); o.y = f2bf(oy);
        *reinterpret_cast<ushort2*>((unsigned short*)outv + (size_t)wid*128 + f) = o;
    }
}

// ---------------- convert fp32 -> bf16 ----------------
__global__ __launch_bounds__(256) void conv_bf16(const float* __restrict__ in, unsigned short* __restrict__ out, int n4){
    int i = blockIdx.x*256 + threadIdx.x;
    if (i < n4){
        float4 v = ld4(in + (size_t)i*4);
        ushort4 o;
        o.x = f2bf(v.x); o.y = f2bf(v.y); o.z = f2bf(v.z); o.w = f2bf(v.w);
        *reinterpret_cast<ushort4*>(out + (size_t)i*4) = o;
    }
}

// ---------------- convert + transpose (+ optional per-source-row scale) ----------------
__global__ __launch_bounds__(256) void conv_bf16_T(const float* __restrict__ in, unsigned short* __restrict__ out,
                                                   int M, int ldout, const float* __restrict__ rscale){
    __shared__ float t[64][65];
    int r0 = blockIdx.x*64, c0 = blockIdx.y*64;
    int tid = threadIdx.x;
    for (int i = tid; i < 64*16; i += 256){
        int r = i >> 4, c4 = (i & 15) * 4;
        float4 v = (r0 + r < M) ? ld4(in + (size_t)(r0+r)*128 + c0 + c4) : make_float4(0,0,0,0);
        if (rscale && r0 + r < M){
            float sc = rscale[r0 + r];
            v.x *= sc; v.y *= sc; v.z *= sc; v.w *= sc;
        }
        t[r][c4+0]=v.x; t[r][c4+1]=v.y; t[r][c4+2]=v.z; t[r][c4+3]=v.w;
    }
    __syncthreads();
    for (int i = tid; i < 64*16; i += 256){
        int c = i >> 4, r4 = (i & 15) * 4;
        if (r0 + r4 < M){
            ushort4 o;
            o.x = f2bf(t[r4+0][c]); o.y = f2bf(t[r4+1][c]);
            o.z = f2bf(t[r4+2][c]); o.w = f2bf(t[r4+3][c]);
            *reinterpret_cast<ushort4*>(out + (size_t)(c0+c)*ldout + r0 + r4) = o;
        }
    }
}

__global__ __launch_bounds__(256) void k_rcp32(const float* __restrict__ zp, float* __restrict__ zinv){
    int n = blockIdx.x*256 + threadIdx.x;
    if (n < NN){
        float s = 0.f;
        #pragma unroll
        for (int y = 0; y < 32; ++y) s += zp[(size_t)y*NN + n];
        zinv[n] = 1.f / s;
    }
}

// ---------------- S-GEMM + exp + z-partials: E[n][k] = exp(SCALE * Kd[n].Q[k]) ----------------
__global__ __launch_bounds__(256) void s_gemm_exp(const unsigned short* __restrict__ Kb,
                                                  const unsigned short* __restrict__ Qb2,
                                                  unsigned short* __restrict__ E, float* __restrict__ zpart){
    __shared__ unsigned short Es[64*68];
    int tid = threadIdx.x;
    int wave = tid >> 6, lane = tid & 63;
    int wm = wave >> 1, wn = wave & 1;
    int n_blk = blockIdx.x*64, k_blk = blockIdx.y*64;
    int l15 = lane & 15;
    int roff = (lane >> 4) * 8;
    const unsigned short* ap0 = Kb + (size_t)(n_blk + wm*32 + l15)*128 + roff;
    const unsigned short* ap1 = ap0 + 16*128;
    const unsigned short* bp0 = Qb2 + (size_t)(k_blk + wn*32 + l15)*128 + roff;
    const unsigned short* bp1 = bp0 + 16*128;
    f32x4 acc00 = (f32x4)0.f, acc01 = (f32x4)0.f, acc10 = (f32x4)0.f, acc11 = (f32x4)0.f;
    #pragma unroll
    for (int r = 0; r < 128; r += 32){
        sh8 a0 = lds8(ap0 + r);
        sh8 a1 = lds8(ap1 + r);
        sh8 b0 = lds8(bp0 + r);
        sh8 b1 = lds8(bp1 + r);
        acc00 = __builtin_amdgcn_mfma_f32_16x16x32_bf16(a0, b0, acc00, 0, 0, 0);
        acc01 = __builtin_amdgcn_mfma_f32_16x16x32_bf16(a0, b1, acc01, 0, 0, 0);
        acc10 = __builtin_amdgcn_mfma_f32_16x16x32_bf16(a1, b0, acc10, 0, 0, 0);
        acc11 = __builtin_amdgcn_mfma_f32_16x16x32_bf16(a1, b1, acc11, 0, 0, 0);
    }
    int rq = (lane >> 4) * 4;
    f32x4 accs[2][2] = {{acc00, acc01},{acc10, acc11}};
    #pragma unroll
    for (int mi = 0; mi < 2; ++mi){
        #pragma unroll
        for (int ni = 0; ni < 2; ++ni){
            f32x4 a = accs[mi][ni];
            int c_loc = wn*32 + ni*16 + l15;
            bool kv = (k_blk + c_loc) < KK;
            #pragma unroll
            for (int reg = 0; reg < 4; ++reg){
                int r_loc = wm*32 + mi*16 + rq + reg;
                float e = kv ? __expf(a[reg]*SCALE) : 0.f;
                Es[r_loc*68 + c_loc] = f2bf(e);
            }
        }
    }
    __syncthreads();
    if (tid < 64){
        int n = n_blk + tid;
        if (n < NN){
            float s = 0.f;
            #pragma unroll 8
            for (int j = 0; j < 64; ++j) s += bf2f(Es[tid*68 + j]);
            zpart[(size_t)blockIdx.y*NN + n] = s;
        }
    }
    for (int i = tid; i < 512; i += 256){
        int r = i >> 3, c8 = (i & 7) * 8;
        if (n_blk + r < NN){
            ushort4 lo = *reinterpret_cast<const ushort4*>(&Es[r*68 + c8]);
            ushort4 hi = *reinterpret_cast<const ushort4*>(&Es[r*68 + c8 + 4]);
            unsigned short* dst = E + (size_t)(n_blk + r)*KP + k_blk + c8;
            *reinterpret_cast<ushort4*>(dst) = lo;
            *reinterpret_cast<ushort4*>(dst + 4) = hi;
        }
    }
}

// ---------------- attn GEMM partials with next-chunk prefetch ----------------
__global__ __launch_bounds__(256) void attn_gemm(const unsigned short* __restrict__ E,
                                                 const unsigned short* __restrict__ Vt,
                                                 float* __restrict__ part){
    __shared__ unsigned short As[64*36];
    int tid = threadIdx.x;
    int wave = tid >> 6, lane = tid & 63;
    int kk0 = blockIdx.x*64;
    int per = (ACHUNKS + ZSPLIT - 1) / ZSPLIT;
    int c0 = blockIdx.y*per;
    int c1 = min(ACHUNKS, c0 + per);
    int l15 = lane & 15;
    int q8 = (lane >> 4) * 8;
    int d0 = wave*32;
    int n_l = tid & 31;
    int k8 = (tid >> 5) * 8;
    f32x4 acc[4][2];
    #pragma unroll
    for (int g = 0; g < 4; ++g){ acc[g][0] = (f32x4)0.f; acc[g][1] = (f32x4)0.f; }
    const unsigned short* ebase = E + (size_t)n_l*KP + kk0 + k8;
    const unsigned short* vb0p = Vt + (size_t)(d0 + l15)*NN + q8;
    const unsigned short* vb1p = vb0p + (size_t)16*NN;
    // prefetch chunk c0
    sh8 etmp = lds8(ebase + (size_t)c0*32*KP);
    sh8 vb0 = lds8(vb0p + c0*32);
    sh8 vb1 = lds8(vb1p + c0*32);
    for (int ch = c0; ch < c1; ++ch){
        unsigned short tmp[8];
        *reinterpret_cast<sh8*>(tmp) = etmp;
        #pragma unroll
        for (int j = 0; j < 8; ++j) As[(k8 + j)*36 + n_l] = tmp[j];
        __syncthreads();
        // issue next chunk's global loads before consuming current
        sh8 etn = (sh8)0, vbn0 = (sh8)0, vbn1 = (sh8)0;
        if (ch + 1 < c1){
            etn  = lds8(ebase + (size_t)(ch+1)*32*KP);
            vbn0 = lds8(vb0p + (ch+1)*32);
            vbn1 = lds8(vb1p + (ch+1)*32);
        }
        #pragma unroll
        for (int g = 0; g < 4; ++g){
            const unsigned short* ap = &As[(g*16 + l15)*36 + q8];
            union { struct { ushort4 lo, hi; } u; sh8 v; } af;
            af.u.lo = *reinterpret_cast<const ushort4*>(ap);
            af.u.hi = *reinterpret_cast<const ushort4*>(ap + 4);
            acc[g][0] = __builtin_amdgcn_mfma_f32_16x16x32_bf16(af.v, vb0, acc[g][0], 0, 0, 0);
            acc[g][1] = __builtin_amdgcn_mfma_f32_16x16x32_bf16(af.v, vb1, acc[g][1], 0, 0, 0);
        }
        __syncthreads();
        etmp = etn; vb0 = vbn0; vb1 = vbn1;
    }
    float* pbase = part + (size_t)blockIdx.y*KK*128;
    int rq = (lane >> 4) * 4;
    #pragma unroll
    for (int g = 0; g < 4; ++g){
        #pragma unroll
        for (int ni = 0; ni < 2; ++ni){
            int d = d0 + ni*16 + l15;
            #pragma unroll
            for (int reg = 0; reg < 4; ++reg){
                int kk = kk0 + g*16 + rq + reg;
                if (kk < KK) pbase[(size_t)kk*128 + d] = acc[g][ni][reg];
            }
        }
    }
}

// ---------------- xout GEMM: double-buffered 64-wide K batches, unchecked E reads ----------------
__global__ __launch_bounds__(256) void xout_gemm(const unsigned short* __restrict__ E,
                                                 const unsigned short* __restrict__ B,
                                                 const float* __restrict__ zinv,
                                                 unsigned short* __restrict__ xr){
    int tid = threadIdx.x;
    int wave = tid >> 6, lane = tid & 63;
    int wm = wave >> 1, wn = wave & 1;
    int m_base = blockIdx.x*64 + wm*32;
    int n_base = blockIdx.y*64 + wn*32;
    int l15 = lane & 15;
    int roff = (lane >> 4) * 8;
    const unsigned short* ap0 = E + (size_t)(m_base + l15)*KP + roff;
    const unsigned short* ap1 = ap0 + (size_t)16*KP;
    const unsigned short* bp0 = B + (size_t)(n_base + l15)*KP + roff;
    const unsigned short* bp1 = bp0 + (size_t)16*KP;
    f32x4 acc00 = (f32x4)0.f, acc01 = (f32x4)0.f, acc10 = (f32x4)0.f, acc11 = (f32x4)0.f;
    sh8 a0 = lds8(ap0),      a1 = lds8(ap1),      a2 = lds8(ap0 + 32), a3 = lds8(ap1 + 32);
    sh8 b0 = lds8(bp0),      b1 = lds8(bp1),      b2 = lds8(bp0 + 32), b3 = lds8(bp1 + 32);
    for (int r = 0; r < KP; r += 64){
        int rn = r + 64;
        sh8 na0 = (sh8)0, na1 = (sh8)0, na2 = (sh8)0, na3 = (sh8)0;
        sh8 nb0 = (sh8)0, nb1 = (sh8)0, nb2 = (sh8)0, nb3 = (sh8)0;
        if (rn < KP){
            na0 = lds8(ap0 + rn);      na1 = lds8(ap1 + rn);
            na2 = lds8(ap0 + rn + 32); na3 = lds8(ap1 + rn + 32);
            nb0 = lds8(bp0 + rn);      nb1 = lds8(bp1 + rn);
            nb2 = lds8(bp0 + rn + 32); nb3 = lds8(bp1 + rn + 32);
        }
        acc00 = __builtin_amdgcn_mfma_f32_16x16x32_bf16(a0, b0, acc00, 0, 0, 0);
        acc01 = __builtin_amdgcn_mfma_f32_16x16x32_bf16(a0, b1, acc01, 0, 0, 0);
        acc10 = __builtin_amdgcn_mfma_f32_16x16x32_bf16(a1, b0, acc10, 0, 0, 0);
        acc11 = __builtin_amdgcn_mfma_f32_16x16x32_bf16(a1, b1, acc11, 0, 0, 0);
        acc00 = __builtin_amdgcn_mfma_f32_16x16x32_bf16(a2, b2, acc00, 0, 0, 0);
        acc01 = __builtin_amdgcn_mfma_f32_16x16x32_bf16(a2, b3, acc01, 0, 0, 0);
        acc10 = __builtin_amdgcn_mfma_f32_16x16x32_bf16(a3, b2, acc10, 0, 0, 0);
        acc11 = __builtin_amdgcn_mfma_f32_16x16x32_bf16(a3, b3, acc11, 0, 0, 0);
        a0 = na0; a1 = na1; a2 = na2; a3 = na3;
        b0 = nb0; b1 = nb1; b2 = nb2; b3 = nb3;
    }
    int rq = (lane >> 4) * 4;
    f32x4 accs[2][2] = {{acc00, acc01},{acc10, acc11}};
    #pragma unroll
    for (int mi = 0; mi < 2; ++mi){
        #pragma unroll
        for (int ni = 0; ni < 2; ++ni){
            f32x4 a = accs[mi][ni];
            int gn = n_base + ni*16 + l15;
            #pragma unroll
            for (int reg = 0; reg < 4; ++reg){
                int gm = m_base + mi*16 + rq + reg;
                if (gm < NN) xr[(size_t)gm*128 + gn] = f2bf(a[reg]*zinv[gm]);
            }
        }
    }
}

// ---------------- LayerNorm over D=128 (with partial-sum input) ----------------
__global__ __launch_bounds__(128) void ln_ker(const float* __restrict__ in, int nparts,
                                              const float* __restrict__ resid,
                                              const float* __restrict__ g, const float* __restrict__ be,
                                              float* __restrict__ out){
    __shared__ float rs[128], rq[128];
    int r = blockIdx.x, t = threadIdx.x;
    float v = 0.f;
    for (int p = 0; p < nparts; ++p) v += in[(size_t)p*KK*128 + r*128 + t];
    if (resid) v += resid[r*128 + t];
    rs[t] = v; rq[t] = v*v;
    __syncthreads();
    for (int off = 64; off > 0; off >>= 1){
        if (t < off){ rs[t] += rs[t+off]; rq[t] += rq[t+off]; }
        __syncthreads();
    }
    float mean = rs[0]*(1.f/128.f);
    float var = rq[0]*(1.f/128.f) - mean*mean;
    out[r*128 + t] = (v - mean)*rsqrtf(var + 1e-5f)*g[t] + be[t];
}

// ---------------- launcher ----------------
extern "C" void kernel_launch(void* const* d_in, const int* in_sizes, int n_in,
                              void* d_out, int out_size, void* d_ws, size_t ws_size,
                              hipStream_t stream){
    cfp x  = (cfp)d_in[0];
    const int* ei = (const int*)d_in[1];
    const int* esrc = ei;
    const int* edst = ei + EE;
    cfp W1=(cfp)d_in[3], b1=(cfp)d_in[4], W2=(cfp)d_in[5], b2=(cfp)d_in[6];
    cfp S =(cfp)d_in[7];
    cfp Wq=(cfp)d_in[8],  bq=(cfp)d_in[9],  Wk=(cfp)d_in[10], bk=(cfp)d_in[11];
    cfp Wv=(cfp)d_in[12], bv=(cfp)d_in[13], Wo=(cfp)d_in[14], bo=(cfp)d_in[15];
    cfp g0=(cfp)d_in[16], be0=(cfp)d_in[17], g1=(cfp)d_in[18], be1=(cfp)d_in[19];
    cfp Wl=(cfp)d_in[20], bl=(cfp)d_in[21], W3=(cfp)d_in[22], b3=(cfp)d_in[23];
    cfp W4=(cfp)d_in[24], b4=(cfp)d_in[25], W5=(cfp)d_in[26], b5=(cfp)d_in[27];

    char* wsb = (char*)d_ws;
    const size_t MB = 1048576;
    int*   deg    = (int*)  (wsb + 0);
    float* dinv   = (float*)(wsb + 81920);
    int*   rows   = (int*)  (wsb + 163840);
    int*   cursor = (int*)  (wsb + 245760);
    int*   col    = (int*)  (wsb + 327680);
    float* Qb     = (float*)(wsb + 2*MB);
    float* o1     = (float*)(wsb + 3*MB);
    float* o2     = (float*)(wsb + 4*MB);
    float* o3     = (float*)(wsb + 5*MB);
    float* xlb    = (float*)(wsb + 6*MB);
    float* zpart  = (float*)(wsb + 7*MB);                 // 32 x NN fp32 = 2.56 MB
    float* zinv   = (float*)(wsb + 10*MB);
    unsigned short* Wts = (unsigned short*)(wsb + 10*MB + 131072);
    unsigned short* Qbf = (unsigned short*)(wsb + 11*MB);
    unsigned short* xlt = (unsigned short*)(wsb + 11*MB + 524288);
    unsigned short* xbf = (unsigned short*)(wsb + 12*MB);
    unsigned short* h1  = (unsigned short*)(wsb + 17*MB);
    unsigned short* h2  = (unsigned short*)(wsb + 22*MB);
    unsigned short* ybuf= (unsigned short*)(wsb + 27*MB);
    unsigned short* Kbf = (unsigned short*)(wsb + 32*MB);
    unsigned short* Vtz = (unsigned short*)(wsb + 37*MB);
    float* NB3    = (float*)(wsb + 42*MB);
    float* part   = (float*)(wsb + 52*MB);                // ZSPLIT x KK x 128 fp32 = 15.6 MiB
    unsigned short* E = (unsigned short*)(wsb + 68*MB);   // [NN x KP] bf16 = 78.1 MiB
    float* outp   = (float*)d_out;
    unsigned short* h3 = xbf;
    unsigned short* h4 = h1;
    unsigned short* xr = Kbf;

    (void)hipMemsetAsync(deg, 0, NN*sizeof(int), stream);
    (void)hipMemsetAsync(cursor, 0, NN*sizeof(int), stream);

    // CSR build
    k_count<<<1250, 256, 0, stream>>>(edst, deg);
    k_dinv<<<79, 256, 0, stream>>>(deg, dinv);
    k_scan<<<1, 1024, 0, stream>>>(deg, rows);
    k_fill<<<1250, 256, 0, stream>>>(esrc, edst, rows, cursor, col);

    // weights -> bf16 transposed; x -> bf16
    conv_wT<<<dim3(2,2,7), 256, 0, stream>>>(W1, W2, Wk, Wv, W3, W4, W5, Wts);
    conv_bf16<<<2500, 256, 0, stream>>>(x, xbf, NN*32);
    unsigned short* W1t = Wts;
    unsigned short* W2t = Wts + 16384;
    unsigned short* Wkt = Wts + 2*16384;
    unsigned short* Wvt = Wts + 3*16384;
    unsigned short* W3t = Wts + 4*16384;
    unsigned short* W4t = Wts + 5*16384;
    unsigned short* W5t = Wts + 6*16384;

    const int GN = 313;   // ceil(NN/64)
    const int GK = 32;    // ceil(KK/64) == KP/64

    // GCN1
    tgemm<<<dim3(GN,2), 256, 0, stream>>>(xbf, NN, W1t, dinv, ybuf);
    gcn_agg_bf<<<5000, 256, 0, stream>>>(ybuf, dinv, rows, col, b1, h1, 1, 0);
    // GCN2 -> h2
    tgemm<<<dim3(GN,2), 256, 0, stream>>>(h1, NN, W2t, dinv, ybuf);
    gcn_agg_bf<<<5000, 256, 0, stream>>>(ybuf, dinv, rows, col, b2, h2, 1, 0);
    // Kd -> Kbf (bf16)
    tgemm<<<dim3(GN,2), 256, 0, stream>>>(h2, NN, Wkt, dinv, ybuf);
    gcn_agg_bf<<<5000, 256, 0, stream>>>(ybuf, dinv, rows, col, bk, Kbf, 0, 0);
    // Q = S@Wq + bq (fp32) -> Qbf
    gemm128<<<GK, 512, 0, stream>>>(S, Wq, Qb, KK, bq, nullptr, 0);
    conv_bf16<<<250, 256, 0, stream>>>(Qb, Qbf, KK*32);
    // E = exp(SCALE * Kd Q^T), z partials
    s_gemm_exp<<<dim3(GN, GK), 256, 0, stream>>>(Kbf, Qbf, E, zpart);
    k_rcp32<<<79, 256, 0, stream>>>(zpart, zinv);
    // Vd -> NB3 (fp32) -> Vtz (transposed bf16, pre-scaled by zinv[n])
    tgemm<<<dim3(GN,2), 256, 0, stream>>>(h2, NN, Wvt, dinv, ybuf);
    gcn_agg_bf<<<5000, 256, 0, stream>>>(ybuf, dinv, rows, col, bv, NB3, 0, 1);
    conv_bf16_T<<<dim3(GN, 2), 256, 0, stream>>>(NB3, Vtz, NN, NN, zinv);
    // attn partials
    attn_gemm<<<dim3(GK, ZSPLIT), 256, 0, stream>>>(E, Vtz, part);
    // out = LN(sum(part) + Q)
    ln_ker<<<KK, 128, 0, stream>>>(part, ZSPLIT, Qb, g0, be0, o1);
    // o2 = o1 + relu(o1@Wo + bo)
    gemm128<<<GK, 512, 0, stream>>>(o1, Wo, o2, KK, bo, o1, 1);
    ln_ker<<<KK, 128, 0, stream>>>(o2, 1, nullptr, g1, be1, o3);
    // xl = o3@Wl + bl -> xlt (transposed bf16, ld KP)
    gemm128<<<GK, 512, 0, stream>>>(o3, Wl, xlb, KK, bl, nullptr, 0);
    conv_bf16_T<<<dim3(GK, 2), 256, 0, stream>>>(xlb, xlt, KK, KP, nullptr);
    // xr[n] = bf16(zinv[n] * E[n] @ xl)
    xout_gemm<<<dim3(GN, 2), 256, 0, stream>>>(E, xlt, zinv, xr);
    // GCN3
    tgemm<<<dim3(GN,2), 256, 0, stream>>>(xr, NN, W3t, dinv, ybuf);
    gcn_agg_bf<<<5000, 256, 0, stream>>>(ybuf, dinv, rows, col, b3, h3, 1, 0);
    // GCN4
    tgemm<<<dim3(GN,2), 256, 0, stream>>>(h3, NN, W4t, dinv, ybuf);
    gcn_agg_bf<<<5000, 256, 0, stream>>>(ybuf, dinv, rows, col, b4, h4, 1, 0);
    // GCN5 -> d_out (fp32)
    tgemm<<<dim3(GN,2), 256, 0, stream>>>(h4, NN, W5t, dinv, ybuf);
    gcn_agg_bf<<<5000, 256, 0, stream>>>(ybuf, dinv, rows, col, b5, outp, 0, 1);
}

// Round 8
// 632.675 us; speedup vs baseline: 1.8111x; 1.0087x over previous
//
#include <hip/hip_runtime.h>

#define NN 20000
#define EE 320000
#define KK 2000
#define KP 2048          // padded K-dim of E (zeros in 2000..2047)
#define SCALE 0.08838834764831845f
#define ZSPLIT 16        // attn_gemm partial slices
#define ACHUNKS 625      // 20000 / 32

typedef const float* cfp;
typedef __attribute__((ext_vector_type(8))) short sh8;
typedef __attribute__((ext_vector_type(4))) float f32x4;

static __device__ __forceinline__ float4 ld4(const float* p){ return *reinterpret_cast<const float4*>(p); }
static __device__ __forceinline__ void st4(float* p, float4 v){ *reinterpret_cast<float4*>(p) = v; }

static __device__ __forceinline__ unsigned short f2bf(float f){
    unsigned int u = __float_as_uint(f);
    u = (u + 0x7FFFu + ((u >> 16) & 1u)) >> 16;
    return (unsigned short)u;
}
static __device__ __forceinline__ float bf2f(unsigned short h){
    return __uint_as_float(((unsigned int)h) << 16);
}
static __device__ __forceinline__ sh8 lds8(const unsigned short* p){ return *reinterpret_cast<const sh8*>(p); }

// ---------------- CSR build ----------------
__global__ __launch_bounds__(256) void k_count(const int* dst, int* deg){
    int i = blockIdx.x*256 + threadIdx.x;
    if (i < EE) atomicAdd(&deg[dst[i]], 1);
}

__global__ __launch_bounds__(256) void k_dinv(const int* deg, float* dinv){
    int n = blockIdx.x*256 + threadIdx.x;
    if (n < NN) dinv[n] = rsqrtf((float)deg[n] + 1.0f);
}

__global__ __launch_bounds__(1024) void k_scan(const int* cnt, int* rows){
    __shared__ int part[1024];
    int t = threadIdx.x;
    int base = t*20;
    int s = 0;
    for (int i = 0; i < 20; ++i){ int idx = base+i; if (idx < NN) s += cnt[idx]; }
    part[t] = s; __syncthreads();
    for (int off = 1; off < 1024; off <<= 1){
        int v = (t >= off) ? part[t-off] : 0;
        __syncthreads();
        part[t] += v;
        __syncthreads();
    }
    int run = part[t] - s;   // exclusive
    for (int i = 0; i < 20; ++i){
        int idx = base+i;
        if (idx < NN){ rows[idx] = run; run += cnt[idx]; }
    }
    if (t == 0) rows[NN] = EE;
}

__global__ __launch_bounds__(256) void k_fill(const int* src, const int* dst, const int* rows,
                                              int* cursor, int* col){
    int i = blockIdx.x*256 + threadIdx.x;
    if (i < EE){
        int d = dst[i];
        int pos = rows[d] + atomicAdd(&cursor[d], 1);
        col[pos] = src[i];
    }
}

// ---------------- weight transpose+convert ----------------
__global__ __launch_bounds__(256) void conv_wT(cfp w0, cfp w1, cfp w2, cfp w3, cfp w4, cfp w5, cfp w6,
                                               unsigned short* wts){
    const float* in;
    switch (blockIdx.z){
        case 0: in = w0; break; case 1: in = w1; break; case 2: in = w2; break;
        case 3: in = w3; break; case 4: in = w4; break; case 5: in = w5; break;
        default: in = w6; break;
    }
    unsigned short* out = wts + (size_t)blockIdx.z*16384;
    __shared__ float t[64][65];
    int r0 = blockIdx.x*64, c0 = blockIdx.y*64;
    int tid = threadIdx.x;
    for (int i = tid; i < 64*16; i += 256){
        int r = i >> 4, c4 = (i & 15) * 4;
        float4 v = ld4(in + (size_t)(r0+r)*128 + c0 + c4);
        t[r][c4+0]=v.x; t[r][c4+1]=v.y; t[r][c4+2]=v.z; t[r][c4+3]=v.w;
    }
    __syncthreads();
    for (int i = tid; i < 64*16; i += 256){
        int c = i >> 4, r4 = (i & 15) * 4;
        ushort4 o;
        o.x = f2bf(t[r4+0][c]); o.y = f2bf(t[r4+1][c]);
        o.z = f2bf(t[r4+2][c]); o.w = f2bf(t[r4+3][c]);
        *reinterpret_cast<ushort4*>(out + (size_t)(c0+c)*128 + r0 + r4) = o;
    }
}

// ---------------- fp32 GEMM (KK-sized only) ----------------
__global__ __launch_bounds__(512) void gemm128(const float* __restrict__ A, const float* __restrict__ Wm,
                                               float* __restrict__ C, int M,
                                               const float* bias, const float* resid, int relu){
    __shared__ __align__(16) float Ws[128*132];
    __shared__ float As[64*129];
    int tid = threadIdx.x;
    int r0 = blockIdx.x*64;
    for (int i = tid; i < 128*32; i += 512){
        int r = i >> 5, c4 = (i & 31) * 4;
        float4 v = ld4(Wm + r*128 + c4);
        st4(&Ws[r*132 + c4], v);
    }
    for (int i = tid; i < 64*32; i += 512){
        int r = i >> 5, c4 = (i & 31) * 4;
        float4 v = (r0 + r < M) ? ld4(A + (size_t)(r0+r)*128 + c4) : make_float4(0,0,0,0);
        As[r*129 + c4+0] = v.x; As[r*129 + c4+1] = v.y;
        As[r*129 + c4+2] = v.z; As[r*129 + c4+3] = v.w;
    }
    __syncthreads();
    int a = tid >> 5;
    int b = tid & 31;
    float acc[4][4] = {};
    #pragma unroll 4
    for (int d = 0; d < 128; ++d){
        float4 w = ld4(&Ws[d*132 + 4*b]);
        float wv[4] = {w.x, w.y, w.z, w.w};
        float av[4];
        #pragma unroll
        for (int i = 0; i < 4; ++i) av[i] = As[(4*a+i)*129 + d];
        #pragma unroll
        for (int i = 0; i < 4; ++i)
            #pragma unroll
            for (int j = 0; j < 4; ++j)
                acc[i][j] += av[i]*wv[j];
    }
    int cc = 4*b;
    #pragma unroll
    for (int i = 0; i < 4; ++i){
        int r = r0 + 4*a + i;
        if (r < M){
            float v[4];
            #pragma unroll
            for (int j = 0; j < 4; ++j) v[j] = acc[i][j];
            if (bias){
                #pragma unroll
                for (int j = 0; j < 4; ++j) v[j] += bias[cc+j];
            }
            if (relu){
                #pragma unroll
                for (int j = 0; j < 4; ++j) v[j] = fmaxf(v[j], 0.f);
            }
            if (resid){
                float4 rv = ld4(resid + (size_t)r*128 + cc);
                v[0]+=rv.x; v[1]+=rv.y; v[2]+=rv.z; v[3]+=rv.w;
            }
            st4(C + (size_t)r*128 + cc, make_float4(v[0],v[1],v[2],v[3]));
        }
    }
}

// ---------------- bf16 MFMA GEMM: C[M x 128] = (A@W)*rscale, bf16 out ----------------
__global__ __launch_bounds__(256) void tgemm(const unsigned short* __restrict__ A, int M,
                                             const unsigned short* __restrict__ Wt,
                                             const float* __restrict__ rscale,
                                             unsigned short* __restrict__ C){
    int tid = threadIdx.x;
    int wave = tid >> 6, lane = tid & 63;
    int wm = wave >> 1, wn = wave & 1;
    int m_base = blockIdx.x*64 + wm*32;
    int n_base = blockIdx.y*64 + wn*32;
    int l15 = lane & 15;
    int roff = (lane >> 4) * 8;
    const unsigned short* ap0 = A + (size_t)(m_base + l15)*128 + roff;
    const unsigned short* ap1 = ap0 + 16*128;
    const unsigned short* b0p = Wt + (size_t)(n_base + l15)*128 + roff;
    const unsigned short* b1p = b0p + 16*128;
    f32x4 acc00 = (f32x4)0.f, acc01 = (f32x4)0.f, acc10 = (f32x4)0.f, acc11 = (f32x4)0.f;
    #pragma unroll
    for (int r = 0; r < 128; r += 32){
        sh8 a0 = lds8(ap0 + r);
        sh8 a1 = lds8(ap1 + r);
        sh8 b0 = lds8(b0p + r);
        sh8 b1 = lds8(b1p + r);
        acc00 = __builtin_amdgcn_mfma_f32_16x16x32_bf16(a0, b0, acc00, 0, 0, 0);
        acc01 = __builtin_amdgcn_mfma_f32_16x16x32_bf16(a0, b1, acc01, 0, 0, 0);
        acc10 = __builtin_amdgcn_mfma_f32_16x16x32_bf16(a1, b0, acc10, 0, 0, 0);
        acc11 = __builtin_amdgcn_mfma_f32_16x16x32_bf16(a1, b1, acc11, 0, 0, 0);
    }
    int rq = (lane >> 4) * 4;
    f32x4 accs[2][2] = {{acc00, acc01},{acc10, acc11}};
    #pragma unroll
    for (int mi = 0; mi < 2; ++mi){
        #pragma unroll
        for (int ni = 0; ni < 2; ++ni){
            f32x4 a = accs[mi][ni];
            int gn = n_base + ni*16 + l15;
            #pragma unroll
            for (int reg = 0; reg < 4; ++reg){
                int gm = m_base + mi*16 + rq + reg;
                if (gm < M) C[(size_t)gm*128 + gn] = f2bf(a[reg] * (rscale ? rscale[gm] : 1.f));
            }
        }
    }
}

// ---------------- GCN aggregation (bf16 in, fp32 accumulate), neighbor unroll 8 ----------------
__global__ __launch_bounds__(256) void gcn_agg_bf(const unsigned short* __restrict__ y, const float* __restrict__ dinv,
                                                  const int* __restrict__ rows, const int* __restrict__ col,
                                                  const float* __restrict__ bias, void* __restrict__ outv,
                                                  int relu, int out_fp32){
    int wid = (int)((blockIdx.x*256 + threadIdx.x) >> 6);
    int lane = threadIdx.x & 63;
    if (wid >= NN) return;
    int f = lane*2;
    ushort2 u = *reinterpret_cast<const ushort2*>(y + (size_t)wid*128 + f);
    float ax = bf2f(u.x), ay = bf2f(u.y);
    int s = rows[wid], e = rows[wid+1];
    int j = s;
    int e8 = s + ((e - s) & ~7);
    for (; j < e8; j += 8){
        ushort2 v[8];
        #pragma unroll
        for (int q = 0; q < 8; ++q){
            int c = col[j+q];
            v[q] = *reinterpret_cast<const ushort2*>(y + (size_t)c*128 + f);
        }
        #pragma unroll
        for (int q = 0; q < 8; ++q){ ax += bf2f(v[q].x); ay += bf2f(v[q].y); }
    }
    for (; j < e; ++j){
        int c0 = col[j];
        ushort2 v0 = *reinterpret_cast<const ushort2*>(y + (size_t)c0*128 + f);
        ax += bf2f(v0.x); ay += bf2f(v0.y);
    }
    float dn = dinv[wid];
    float ox = ax*dn + bias[f];
    float oy = ay*dn + bias[f+1];
    if (relu){ ox = fmaxf(ox, 0.f); oy = fmaxf(oy, 0.f); }
    if (out_fp32){
        *reinterpret_cast<float2*>((float*)outv + (size_t)wid*128 + f) = make_float2(ox, oy);
    } else {
        ushort2 o; o.x = f2bf(ox); o.y = f2bf(oy);
        *reinterpret_cast<ushort2*>((unsigned short*)outv + (size_t)wid*128 + f) = o;
    }
}

// ---------------- convert fp32 -> bf16 ----------------
__global__ __launch_bounds__(256) void conv_bf16(const float* __restrict__ in, unsigned short* __restrict__ out, int n4){
    int i = blockIdx.x*256 + threadIdx.x;
    if (i < n4){
        float4 v = ld4(in + (size_t)i*4);
        ushort4 o;
        o.x = f2bf(v.x); o.y = f2bf(v.y); o.z = f2bf(v.z); o.w = f2bf(v.w);
        *reinterpret_cast<ushort4*>(out + (size_t)i*4) = o;
    }
}

// ---------------- convert + transpose (+ optional per-source-row scale) ----------------
__global__ __launch_bounds__(256) void conv_bf16_T(const float* __restrict__ in, unsigned short* __restrict__ out,
                                                   int M, int ldout, const float* __restrict__ rscale){
    __shared__ float t[64][65];
    int r0 = blockIdx.x*64, c0 = blockIdx.y*64;
    int tid = threadIdx.x;
    for (int i = tid; i < 64*16; i += 256){
        int r = i >> 4, c4 = (i & 15) * 4;
        float4 v = (r0 + r < M) ? ld4(in + (size_t)(r0+r)*128 + c0 + c4) : make_float4(0,0,0,0);
        if (rscale && r0 + r < M){
            float sc = rscale[r0 + r];
            v.x *= sc; v.y *= sc; v.z *= sc; v.w *= sc;
        }
        t[r][c4+0]=v.x; t[r][c4+1]=v.y; t[r][c4+2]=v.z; t[r][c4+3]=v.w;
    }
    __syncthreads();
    for (int i = tid; i < 64*16; i += 256){
        int c = i >> 4, r4 = (i & 15) * 4;
        if (r0 + r4 < M){
            ushort4 o;
            o.x = f2bf(t[r4+0][c]); o.y = f2bf(t[r4+1][c]);
            o.z = f2bf(t[r4+2][c]); o.w = f2bf(t[r4+3][c]);
            *reinterpret_cast<ushort4*>(out + (size_t)(c0+c)*ldout + r0 + r4) = o;
        }
    }
}

// ---------------- z reduction: zinv[n] = 1/sum, zdinv[n] = zinv[n]*dinv[n] ----------------
__global__ __launch_bounds__(256) void k_rcp32(const float* __restrict__ zp, const float* __restrict__ dinv,
                                               float* __restrict__ zinv, float* __restrict__ zdinv){
    int n = blockIdx.x*256 + threadIdx.x;
    if (n < NN){
        float s = 0.f;
        #pragma unroll
        for (int y = 0; y < 32; ++y) s += zp[(size_t)y*NN + n];
        float zi = 1.f / s;
        zinv[n] = zi;
        zdinv[n] = zi * dinv[n];
    }
}

// ---------------- S-GEMM + exp + z-partials ----------------
__global__ __launch_bounds__(256) void s_gemm_exp(const unsigned short* __restrict__ Kb,
                                                  const unsigned short* __restrict__ Qb2,
                                                  unsigned short* __restrict__ E, float* __restrict__ zpart){
    __shared__ unsigned short Es[64*68];
    int tid = threadIdx.x;
    int wave = tid >> 6, lane = tid & 63;
    int wm = wave >> 1, wn = wave & 1;
    int n_blk = blockIdx.x*64, k_blk = blockIdx.y*64;
    int l15 = lane & 15;
    int roff = (lane >> 4) * 8;
    const unsigned short* ap0 = Kb + (size_t)(n_blk + wm*32 + l15)*128 + roff;
    const unsigned short* ap1 = ap0 + 16*128;
    const unsigned short* bp0 = Qb2 + (size_t)(k_blk + wn*32 + l15)*128 + roff;
    const unsigned short* bp1 = bp0 + 16*128;
    f32x4 acc00 = (f32x4)0.f, acc01 = (f32x4)0.f, acc10 = (f32x4)0.f, acc11 = (f32x4)0.f;
    #pragma unroll
    for (int r = 0; r < 128; r += 32){
        sh8 a0 = lds8(ap0 + r);
        sh8 a1 = lds8(ap1 + r);
        sh8 b0 = lds8(bp0 + r);
        sh8 b1 = lds8(bp1 + r);
        acc00 = __builtin_amdgcn_mfma_f32_16x16x32_bf16(a0, b0, acc00, 0, 0, 0);
        acc01 = __builtin_amdgcn_mfma_f32_16x16x32_bf16(a0, b1, acc01, 0, 0, 0);
        acc10 = __builtin_amdgcn_mfma_f32_16x16x32_bf16(a1, b0, acc10, 0, 0, 0);
        acc11 = __builtin_amdgcn_mfma_f32_16x16x32_bf16(a1, b1, acc11, 0, 0, 0);
    }
    int rq = (lane >> 4) * 4;
    f32x4 accs[2][2] = {{acc00, acc01},{acc10, acc11}};
    #pragma unroll
    for (int mi = 0; mi < 2; ++mi){
        #pragma unroll
        for (int ni = 0; ni < 2; ++ni){
            f32x4 a = accs[mi][ni];
            int c_loc = wn*32 + ni*16 + l15;
            bool kv = (k_blk + c_loc) < KK;
            #pragma unroll
            for (int reg = 0; reg < 4; ++reg){
                int r_loc = wm*32 + mi*16 + rq + reg;
                float e = kv ? __expf(a[reg]*SCALE) : 0.f;
                Es[r_loc*68 + c_loc] = f2bf(e);
            }
        }
    }
    __syncthreads();
    if (tid < 64){
        int n = n_blk + tid;
        if (n < NN){
            float s = 0.f;
            #pragma unroll 8
            for (int j = 0; j < 64; ++j) s += bf2f(Es[tid*68 + j]);
            zpart[(size_t)blockIdx.y*NN + n] = s;
        }
    }
    for (int i = tid; i < 512; i += 256){
        int r = i >> 3, c8 = (i & 7) * 8;
        if (n_blk + r < NN){
            ushort4 lo = *reinterpret_cast<const ushort4*>(&Es[r*68 + c8]);
            ushort4 hi = *reinterpret_cast<const ushort4*>(&Es[r*68 + c8 + 4]);
            unsigned short* dst = E + (size_t)(n_blk + r)*KP + k_blk + c8;
            *reinterpret_cast<ushort4*>(dst) = lo;
            *reinterpret_cast<ushort4*>(dst + 4) = hi;
        }
    }
}

// ---------------- attn GEMM partials with next-chunk prefetch ----------------
__global__ __launch_bounds__(256) void attn_gemm(const unsigned short* __restrict__ E,
                                                 const unsigned short* __restrict__ Vt,
                                                 float* __restrict__ part){
    __shared__ unsigned short As[64*36];
    int tid = threadIdx.x;
    int wave = tid >> 6, lane = tid & 63;
    int kk0 = blockIdx.x*64;
    int per = (ACHUNKS + ZSPLIT - 1) / ZSPLIT;
    int c0 = blockIdx.y*per;
    int c1 = min(ACHUNKS, c0 + per);
    int l15 = lane & 15;
    int q8 = (lane >> 4) * 8;
    int d0 = wave*32;
    int n_l = tid & 31;
    int k8 = (tid >> 5) * 8;
    f32x4 acc[4][2];
    #pragma unroll
    for (int g = 0; g < 4; ++g){ acc[g][0] = (f32x4)0.f; acc[g][1] = (f32x4)0.f; }
    const unsigned short* ebase = E + (size_t)n_l*KP + kk0 + k8;
    const unsigned short* vb0p = Vt + (size_t)(d0 + l15)*NN + q8;
    const unsigned short* vb1p = vb0p + (size_t)16*NN;
    sh8 etmp = lds8(ebase + (size_t)c0*32*KP);
    sh8 vb0 = lds8(vb0p + c0*32);
    sh8 vb1 = lds8(vb1p + c0*32);
    for (int ch = c0; ch < c1; ++ch){
        unsigned short tmp[8];
        *reinterpret_cast<sh8*>(tmp) = etmp;
        #pragma unroll
        for (int j = 0; j < 8; ++j) As[(k8 + j)*36 + n_l] = tmp[j];
        __syncthreads();
        sh8 etn = (sh8)0, vbn0 = (sh8)0, vbn1 = (sh8)0;
        if (ch + 1 < c1){
            etn  = lds8(ebase + (size_t)(ch+1)*32*KP);
            vbn0 = lds8(vb0p + (ch+1)*32);
            vbn1 = lds8(vb1p + (ch+1)*32);
        }
        #pragma unroll
        for (int g = 0; g < 4; ++g){
            const unsigned short* ap = &As[(g*16 + l15)*36 + q8];
            union { struct { ushort4 lo, hi; } u; sh8 v; } af;
            af.u.lo = *reinterpret_cast<const ushort4*>(ap);
            af.u.hi = *reinterpret_cast<const ushort4*>(ap + 4);
            acc[g][0] = __builtin_amdgcn_mfma_f32_16x16x32_bf16(af.v, vb0, acc[g][0], 0, 0, 0);
            acc[g][1] = __builtin_amdgcn_mfma_f32_16x16x32_bf16(af.v, vb1, acc[g][1], 0, 0, 0);
        }
        __syncthreads();
        etmp = etn; vb0 = vbn0; vb1 = vbn1;
    }
    float* pbase = part + (size_t)blockIdx.y*KK*128;
    int rq = (lane >> 4) * 4;
    #pragma unroll
    for (int g = 0; g < 4; ++g){
        #pragma unroll
        for (int ni = 0; ni < 2; ++ni){
            int d = d0 + ni*16 + l15;
            #pragma unroll
            for (int reg = 0; reg < 4; ++reg){
                int kk = kk0 + g*16 + rq + reg;
                if (kk < KK) pbase[(size_t)kk*128 + d] = acc[g][ni][reg];
            }
        }
    }
}

// ---------------- xout GEMM: K-split x2, db 64-wide batches, fp32 partials ----------------
__global__ __launch_bounds__(256) void xout_gemm(const unsigned short* __restrict__ E,
                                                 const unsigned short* __restrict__ B,
                                                 float* __restrict__ xpart){
    int tid = threadIdx.x;
    int wave = tid >> 6, lane = tid & 63;
    int wm = wave >> 1, wn = wave & 1;
    int m_base = blockIdx.x*64 + wm*32;
    int n_base = blockIdx.y*64 + wn*32;
    int kz = blockIdx.z*1024;
    int l15 = lane & 15;
    int roff = (lane >> 4) * 8;
    const unsigned short* ap0 = E + (size_t)(m_base + l15)*KP + kz + roff;
    const unsigned short* ap1 = ap0 + (size_t)16*KP;
    const unsigned short* bp0 = B + (size_t)(n_base + l15)*KP + kz + roff;
    const unsigned short* bp1 = bp0 + (size_t)16*KP;
    f32x4 acc00 = (f32x4)0.f, acc01 = (f32x4)0.f, acc10 = (f32x4)0.f, acc11 = (f32x4)0.f;
    sh8 a0 = lds8(ap0),      a1 = lds8(ap1),      a2 = lds8(ap0 + 32), a3 = lds8(ap1 + 32);
    sh8 b0 = lds8(bp0),      b1 = lds8(bp1),      b2 = lds8(bp0 + 32), b3 = lds8(bp1 + 32);
    for (int r = 0; r < 1024; r += 64){
        int rn = r + 64;
        sh8 na0 = (sh8)0, na1 = (sh8)0, na2 = (sh8)0, na3 = (sh8)0;
        sh8 nb0 = (sh8)0, nb1 = (sh8)0, nb2 = (sh8)0, nb3 = (sh8)0;
        if (rn < 1024){
            na0 = lds8(ap0 + rn);      na1 = lds8(ap1 + rn);
            na2 = lds8(ap0 + rn + 32); na3 = lds8(ap1 + rn + 32);
            nb0 = lds8(bp0 + rn);      nb1 = lds8(bp1 + rn);
            nb2 = lds8(bp0 + rn + 32); nb3 = lds8(bp1 + rn + 32);
        }
        acc00 = __builtin_amdgcn_mfma_f32_16x16x32_bf16(a0, b0, acc00, 0, 0, 0);
        acc01 = __builtin_amdgcn_mfma_f32_16x16x32_bf16(a0, b1, acc01, 0, 0, 0);
        acc10 = __builtin_amdgcn_mfma_f32_16x16x32_bf16(a1, b0, acc10, 0, 0, 0);
        acc11 = __builtin_amdgcn_mfma_f32_16x16x32_bf16(a1, b1, acc11, 0, 0, 0);
        acc00 = __builtin_amdgcn_mfma_f32_16x16x32_bf16(a2, b2, acc00, 0, 0, 0);
        acc01 = __builtin_amdgcn_mfma_f32_16x16x32_bf16(a2, b3, acc01, 0, 0, 0);
        acc10 = __builtin_amdgcn_mfma_f32_16x16x32_bf16(a3, b2, acc10, 0, 0, 0);
        acc11 = __builtin_amdgcn_mfma_f32_16x16x32_bf16(a3, b3, acc11, 0, 0, 0);
        a0 = na0; a1 = na1; a2 = na2; a3 = na3;
        b0 = nb0; b1 = nb1; b2 = nb2; b3 = nb3;
    }
    float* pbase = xpart + (size_t)blockIdx.z*NN*128;
    int rq = (lane >> 4) * 4;
    f32x4 accs[2][2] = {{acc00, acc01},{acc10, acc11}};
    #pragma unroll
    for (int mi = 0; mi < 2; ++mi){
        #pragma unroll
        for (int ni = 0; ni < 2; ++ni){
            f32x4 a = accs[mi][ni];
            int gn = n_base + ni*16 + l15;
            #pragma unroll
            for (int reg = 0; reg < 4; ++reg){
                int gm = m_base + mi*16 + rq + reg;
                if (gm < NN) pbase[(size_t)gm*128 + gn] = a[reg];
            }
        }
    }
}

// ---------------- xout reduce: ybuf = bf16(zdinv[n] * (p0 + p1)) ----------------
__global__ __launch_bounds__(256) void xred(const float* __restrict__ xp, const float* __restrict__ zdinv,
                                            unsigned short* __restrict__ out){
    int i = blockIdx.x*256 + threadIdx.x;
    if (i < NN*32){
        int row = i >> 5;
        float4 p0 = ld4(xp + (size_t)i*4);
        float4 p1 = ld4(xp + (size_t)NN*128 + (size_t)i*4);
        float sc = zdinv[row];
        ushort4 o;
        o.x = f2bf((p0.x + p1.x)*sc);
        o.y = f2bf((p0.y + p1.y)*sc);
        o.z = f2bf((p0.z + p1.z)*sc);
        o.w = f2bf((p0.w + p1.w)*sc);
        *reinterpret_cast<ushort4*>(out + (size_t)i*4) = o;
    }
}

// ---------------- LayerNorm over D=128 (with partial-sum input) ----------------
__global__ __launch_bounds__(128) void ln_ker(const float* __restrict__ in, int nparts,
                                              const float* __restrict__ resid,
                                              const float* __restrict__ g, const float* __restrict__ be,
                                              float* __restrict__ out){
    __shared__ float rs[128], rq[128];
    int r = blockIdx.x, t = threadIdx.x;
    float v = 0.f;
    for (int p = 0; p < nparts; ++p) v += in[(size_t)p*KK*128 + r*128 + t];
    if (resid) v += resid[r*128 + t];
    rs[t] = v; rq[t] = v*v;
    __syncthreads();
    for (int off = 64; off > 0; off >>= 1){
        if (t < off){ rs[t] += rs[t+off]; rq[t] += rq[t+off]; }
        __syncthreads();
    }
    float mean = rs[0]*(1.f/128.f);
    float var = rq[0]*(1.f/128.f) - mean*mean;
    out[r*128 + t] = (v - mean)*rsqrtf(var + 1e-5f)*g[t] + be[t];
}

// ---------------- launcher ----------------
extern "C" void kernel_launch(void* const* d_in, const int* in_sizes, int n_in,
                              void* d_out, int out_size, void* d_ws, size_t ws_size,
                              hipStream_t stream){
    cfp x  = (cfp)d_in[0];
    const int* ei = (const int*)d_in[1];
    const int* esrc = ei;
    const int* edst = ei + EE;
    cfp W1=(cfp)d_in[3], b1=(cfp)d_in[4], W2=(cfp)d_in[5], b2=(cfp)d_in[6];
    cfp S =(cfp)d_in[7];
    cfp Wq=(cfp)d_in[8],  bq=(cfp)d_in[9],  Wk=(cfp)d_in[10], bk=(cfp)d_in[11];
    cfp Wv=(cfp)d_in[12], bv=(cfp)d_in[13], Wo=(cfp)d_in[14], bo=(cfp)d_in[15];
    cfp g0=(cfp)d_in[16], be0=(cfp)d_in[17], g1=(cfp)d_in[18], be1=(cfp)d_in[19];
    cfp Wl=(cfp)d_in[20], bl=(cfp)d_in[21], W3=(cfp)d_in[22], b3=(cfp)d_in[23];
    cfp W4=(cfp)d_in[24], b4=(cfp)d_in[25], W5=(cfp)d_in[26], b5=(cfp)d_in[27];

    char* wsb = (char*)d_ws;
    const size_t MB = 1048576;
    int*   deg    = (int*)  (wsb + 0);
    float* dinv   = (float*)(wsb + 81920);
    int*   rows   = (int*)  (wsb + 163840);
    int*   cursor = (int*)  (wsb + 245760);
    int*   col    = (int*)  (wsb + 327680);
    float* Qb     = (float*)(wsb + 2*MB);
    float* o1     = (float*)(wsb + 3*MB);    // also xl3 (fp32)
    float* o2     = (float*)(wsb + 4*MB);
    float* o3     = (float*)(wsb + 5*MB);
    float* xlb    = (float*)(wsb + 6*MB);
    float* zpart  = (float*)(wsb + 7*MB);                 // 32 x NN fp32
    float* zinv   = (float*)(wsb + 10*MB);
    float* zdinv  = (float*)(wsb + 10*MB + 131072);
    unsigned short* Wts  = (unsigned short*)(wsb + 10*MB + 262144);
    unsigned short* Qbf  = (unsigned short*)(wsb + 11*MB);
    unsigned short* xlt3 = (unsigned short*)(wsb + 11*MB + 524288);  // [128 x KP] bf16
    unsigned short* xbf = (unsigned short*)(wsb + 12*MB); // also h3
    unsigned short* h1  = (unsigned short*)(wsb + 17*MB); // also h4
    unsigned short* h2  = (unsigned short*)(wsb + 22*MB);
    unsigned short* ybuf= (unsigned short*)(wsb + 27*MB);
    unsigned short* Kbf = (unsigned short*)(wsb + 32*MB);
    unsigned short* Vtz = (unsigned short*)(wsb + 37*MB);
    // time-aliased region 42..62 MiB: NB3 (Vd fp32, 9.8 MiB) -> part (16 MiB) -> xpart (19.6 MiB)
    float* NB3    = (float*)(wsb + 42*MB);
    float* part   = (float*)(wsb + 42*MB);
    float* xpart  = (float*)(wsb + 42*MB);
    unsigned short* E = (unsigned short*)(wsb + 62*MB);   // [NN x KP] bf16 = 78.1 MiB -> ends ~140.1 MiB
    float* outp   = (float*)d_out;
    unsigned short* h3 = xbf;
    unsigned short* h4 = h1;

    (void)hipMemsetAsync(deg, 0, NN*sizeof(int), stream);
    (void)hipMemsetAsync(cursor, 0, NN*sizeof(int), stream);
    (void)hipMemsetAsync(xlt3, 0, 128*KP*sizeof(unsigned short), stream);  // pad cols must be finite

    // CSR build
    k_count<<<1250, 256, 0, stream>>>(edst, deg);
    k_dinv<<<79, 256, 0, stream>>>(deg, dinv);
    k_scan<<<1, 1024, 0, stream>>>(deg, rows);
    k_fill<<<1250, 256, 0, stream>>>(esrc, edst, rows, cursor, col);

    // weights -> bf16 transposed; x -> bf16
    conv_wT<<<dim3(2,2,7), 256, 0, stream>>>(W1, W2, Wk, Wv, W3, W4, W5, Wts);
    conv_bf16<<<2500, 256, 0, stream>>>(x, xbf, NN*32);
    unsigned short* W1t = Wts;
    unsigned short* W2t = Wts + 16384;
    unsigned short* Wkt = Wts + 2*16384;
    unsigned short* Wvt = Wts + 3*16384;
    unsigned short* W4t = Wts + 5*16384;
    unsigned short* W5t = Wts + 6*16384;

    const int GN = 313;   // ceil(NN/64)
    const int GK = 32;    // ceil(KK/64) == KP/64

    // GCN1
    tgemm<<<dim3(GN,2), 256, 0, stream>>>(xbf, NN, W1t, dinv, ybuf);
    gcn_agg_bf<<<5000, 256, 0, stream>>>(ybuf, dinv, rows, col, b1, h1, 1, 0);
    // GCN2 -> h2
    tgemm<<<dim3(GN,2), 256, 0, stream>>>(h1, NN, W2t, dinv, ybuf);
    gcn_agg_bf<<<5000, 256, 0, stream>>>(ybuf, dinv, rows, col, b2, h2, 1, 0);
    // Kd -> Kbf (bf16)
    tgemm<<<dim3(GN,2), 256, 0, stream>>>(h2, NN, Wkt, dinv, ybuf);
    gcn_agg_bf<<<5000, 256, 0, stream>>>(ybuf, dinv, rows, col, bk, Kbf, 0, 0);
    // Q = S@Wq + bq (fp32) -> Qbf
    gemm128<<<GK, 512, 0, stream>>>(S, Wq, Qb, KK, bq, nullptr, 0);
    conv_bf16<<<250, 256, 0, stream>>>(Qb, Qbf, KK*32);
    // E = exp(SCALE * Kd Q^T), z partials
    s_gemm_exp<<<dim3(GN, GK), 256, 0, stream>>>(Kbf, Qbf, E, zpart);
    k_rcp32<<<79, 256, 0, stream>>>(zpart, dinv, zinv, zdinv);
    // Vd -> NB3 (fp32) -> Vtz (transposed bf16, pre-scaled by zinv[n])
    tgemm<<<dim3(GN,2), 256, 0, stream>>>(h2, NN, Wvt, dinv, ybuf);
    gcn_agg_bf<<<5000, 256, 0, stream>>>(ybuf, dinv, rows, col, bv, NB3, 0, 1);
    conv_bf16_T<<<dim3(GN, 2), 256, 0, stream>>>(NB3, Vtz, NN, NN, zinv);
    // attn partials (NB3 dead now; part aliases it)
    attn_gemm<<<dim3(GK, ZSPLIT), 256, 0, stream>>>(E, Vtz, part);
    // out = LN(sum(part) + Q)
    ln_ker<<<KK, 128, 0, stream>>>(part, ZSPLIT, Qb, g0, be0, o1);
    // o2 = o1 + relu(o1@Wo + bo)
    gemm128<<<GK, 512, 0, stream>>>(o1, Wo, o2, KK, bo, o1, 1);
    ln_ker<<<KK, 128, 0, stream>>>(o2, 1, nullptr, g1, be1, o3);
    // xl = o3@Wl + bl ; xl3 = xl @ W3  (GCN3 weight folded into the seed side)
    gemm128<<<GK, 512, 0, stream>>>(o3, Wl, xlb, KK, bl, nullptr, 0);
    gemm128<<<GK, 512, 0, stream>>>(xlb, W3, o1, KK, nullptr, nullptr, 0);
    conv_bf16_T<<<dim3(GK, 2), 256, 0, stream>>>(o1, xlt3, KK, KP, nullptr);
    // ybuf[n] = bf16(zinv*dinv*(E[n] @ xl3))  == GCN3 pre-agg activations
    xout_gemm<<<dim3(GN, 2, 2), 256, 0, stream>>>(E, xlt3, xpart);
    xred<<<2500, 256, 0, stream>>>(xpart, zdinv, ybuf);
    // GCN3 aggregation
    gcn_agg_bf<<<5000, 256, 0, stream>>>(ybuf, dinv, rows, col, b3, h3, 1, 0);
    // GCN4
    tgemm<<<dim3(GN,2), 256, 0, stream>>>(h3, NN, W4t, dinv, ybuf);
    gcn_agg_bf<<<5000, 256, 0, stream>>>(ybuf, dinv, rows, col, b4, h4, 1, 0);
    // GCN5 -> d_out (fp32)
    tgemm<<<dim3(GN,2), 256, 0, stream>>>(h4, NN, W5t, dinv, ybuf);
    gcn_agg_bf<<<5000, 256, 0, stream>>>(ybuf, dinv, rows, col, b5, outp, 0, 1);
}